// Round 3
// baseline (435.511 us; speedup 1.0000x reference)
//
#include <hip/hip_runtime.h>

#define NB   32
#define NN   100000
#define NE   1000000
#define HD   64
#define AD   5
#define NL   3
#define NRL  231      // N_REL + 1
#define NTM  365
#define NOUT 228096   // 32 * 7128
#define NBLK1 391     // ceil(NN/256)

// meta packing: w0 = src | (rel<<17) | (cls<<25) ; w1 = ta | (q<<9)

// bf16 helpers (hidden stored as bf16 to halve gather traffic)
__device__ __forceinline__ float bflo(unsigned u) { return __uint_as_float(u << 16); }
__device__ __forceinline__ float bfhi(unsigned u) { return __uint_as_float(u & 0xffff0000u); }
__device__ __forceinline__ unsigned packbf2(float x, float y) {
    unsigned ux = __float_as_uint(x), uy = __float_as_uint(y);
    ux = (ux + 0x7fffu + ((ux >> 16) & 1u)) >> 16;
    uy = (uy + 0x7fffu + ((uy >> 16) & 1u)) >> 16;
    return ux | (uy << 16);
}

using vbf8  = __attribute__((ext_vector_type(8))) short;   // 8 bf16 (4 VGPRs) MFMA A/B frag
using f32x4 = __attribute__((ext_vector_type(4))) float;   // MFMA C/D frag

// ---------------------------------------------------------------------------
// WTB: W in bf16 split (hi/lo) laid out as MFMA B-fragments.
// flat idx = ((((c*2 + hl)*2 + ks)*4 + nt)*64 + lane)*8 ushorts
// value(lane, j) = W_c[h = nt*16 + (lane&15)][k = ks*32 + (lane>>4)*8 + j]
// c: 0=Wf(pos) 1=Wn(zero) 2=Wp(neg); hl: 0=hi 1=residual
__global__ __launch_bounds__(256) void prep_wtb_kernel(
    const float* __restrict__ Wp, const float* __restrict__ Wn,
    const float* __restrict__ Wf, ushort* __restrict__ WTB)
{
    int i = blockIdx.x * 256 + threadIdx.x;
    if (i >= 3072) return;
    int lane = i & 63;
    int nt = (i >> 6) & 3;
    int ks = (i >> 8) & 1;
    int hl = (i >> 9) & 1;
    int c  = i >> 10;
    const float* W = (c == 0) ? Wf : (c == 1 ? Wn : Wp);
    int h  = nt * 16 + (lane & 15);
    int k0 = ks * 32 + (lane >> 4) * 8;
    unsigned up[4];
    #pragma unroll
    for (int j = 0; j < 4; ++j) {
        float x = W[h * 64 + k0 + 2 * j];
        float y = W[h * 64 + k0 + 2 * j + 1];
        unsigned pb = packbf2(x, y);
        if (hl) {
            float rx = x - bflo(pb);
            float ry = y - bfhi(pb);
            pb = packbf2(rx, ry);
        }
        up[j] = pb;
    }
    *(uint4*)(WTB + (size_t)i * 8) = make_uint4(up[0], up[1], up[2], up[3]);
}

// ---------------------------------------------------------------------------
__global__ __launch_bounds__(256) void prep_tables_kernel(
    const float* __restrict__ rela_embed,   // [3][231][64]
    const float* __restrict__ W1,           // [3][5][192]
    float* __restrict__ Trel,               // [3][231][8]
    float* __restrict__ Tq)                 // [3][231][8]
{
    int l = blockIdx.x;
    int r = threadIdx.x;
    if (r >= NRL) return;
    const float4* rrow = (const float4*)(rela_embed + ((size_t)l * NRL + r) * HD);
    const float* W1l = W1 + (size_t)l * AD * 192;
    float tr[AD] = {0,0,0,0,0}, tq[AD] = {0,0,0,0,0};
    #pragma unroll
    for (int k4 = 0; k4 < 16; ++k4) {
        float4 x = rrow[k4];
        #pragma unroll
        for (int a = 0; a < AD; ++a) {
            const float* wr = W1l + a * 192 + 64 + k4 * 4;
            const float* wq = W1l + a * 192 + 128 + k4 * 4;
            tr[a] = fmaf(x.x, wr[0], tr[a]); tr[a] = fmaf(x.y, wr[1], tr[a]);
            tr[a] = fmaf(x.z, wr[2], tr[a]); tr[a] = fmaf(x.w, wr[3], tr[a]);
            tq[a] = fmaf(x.x, wq[0], tq[a]); tq[a] = fmaf(x.y, wq[1], tq[a]);
            tq[a] = fmaf(x.z, wq[2], tq[a]); tq[a] = fmaf(x.w, wq[3], tq[a]);
        }
    }
    float* tro = Trel + ((size_t)l * NRL + r) * 8;
    float* tqo = Tq   + ((size_t)l * NRL + r) * 8;
    #pragma unroll
    for (int a = 0; a < AD; ++a) { tro[a] = tr[a]; tqo[a] = tq[a]; }
    tro[5] = tro[6] = tro[7] = 0.f;
    tqo[5] = tqo[6] = tqo[7] = 0.f;
}

// ---------------------------------------------------------------------------
// Counting sort by dst (dst-only: long segments keep MLP alive — R8 lesson)
__global__ __launch_bounds__(256) void hist_kernel(
    const int* __restrict__ dst_idx, int* __restrict__ deg)
{
    int e = blockIdx.x * 256 + threadIdx.x;
    if (e < NE) atomicAdd(&deg[dst_idx[e]], 1);
}

__global__ __launch_bounds__(256) void scan1_kernel(
    const int* __restrict__ deg, int* __restrict__ tmp, int* __restrict__ bsum)
{
    __shared__ int s[256];
    int tid = threadIdx.x;
    int i = blockIdx.x * 256 + tid;
    int v = (i < NN) ? deg[i] : 0;
    s[tid] = v;
    __syncthreads();
    #pragma unroll
    for (int st = 1; st < 256; st <<= 1) {
        int t = (tid >= st) ? s[tid - st] : 0;
        __syncthreads();
        s[tid] += t;
        __syncthreads();
    }
    if (i < NN) tmp[i] = s[tid];
    if (tid == 255) bsum[blockIdx.x] = s[255];
}

__global__ __launch_bounds__(512) void scan2_kernel(
    const int* __restrict__ bsum, int* __restrict__ bpref)
{
    __shared__ int s[512];
    int tid = threadIdx.x;
    int v = (tid < NBLK1) ? bsum[tid] : 0;
    s[tid] = v;
    __syncthreads();
    #pragma unroll
    for (int st = 1; st < 512; st <<= 1) {
        int t = (tid >= st) ? s[tid - st] : 0;
        __syncthreads();
        s[tid] += t;
        __syncthreads();
    }
    if (tid < NBLK1) bpref[tid] = s[tid] - v;  // exclusive
}

__global__ __launch_bounds__(256) void scan3_kernel(
    const int* __restrict__ deg, const int* __restrict__ tmp,
    const int* __restrict__ bpref, int* __restrict__ off, int* __restrict__ cursor)
{
    int i = blockIdx.x * 256 + threadIdx.x;
    if (i >= NN) return;
    int incl = tmp[i] + bpref[i >> 8];
    off[i + 1] = incl;
    cursor[i] = incl - deg[i];
    if (i == 0) off[0] = 0;
}

// scatter into dst-sorted order. score0 is NOT computed here anymore:
// scattering a second 4B stream doubled the random-write cacheline
// amplification (98 MB WRITE_SIZE for 12 MB payload). score0 now comes
// from a linear pass over sorted meta (score0_lin_kernel).
__global__ __launch_bounds__(256) void sort_scatter_kernel(
    const int* __restrict__ dst_idx, const int* __restrict__ src_idx,
    const int* __restrict__ rel_idx, const int* __restrict__ rel_time,
    const int* __restrict__ batch_idx, const int* __restrict__ query_rel,
    int* __restrict__ cursor, int2* __restrict__ meta)
{
    int e = blockIdx.x * 256 + threadIdx.x;
    if (e >= NE) return;
    int d = dst_idx[e];
    int rt = rel_time[e];
    int cls = (rt > 0) ? 0 : ((rt == 0) ? 1 : 2);
    int ta = (rt < 0) ? -rt : rt;
    int rel = rel_idx[e];
    int q = query_rel[batch_idx[e]];
    int pos = atomicAdd(&cursor[d], 1);
    int2 m;
    m.x = src_idx[e] | (rel << 17) | (cls << 25);
    m.y = ta | (q << 9);
    meta[pos] = m;
}

// linear layer-0 score fill: meta read coalesced, score written coalesced.
// Tables Trel0/Tq0 are ~59 KB total -> L1/L2 resident.
__global__ __launch_bounds__(256) void score0_lin_kernel(
    const int2* __restrict__ meta,
    const float* __restrict__ Trel0, const float* __restrict__ Tq0,
    const float* __restrict__ W2,
    float* __restrict__ score)
{
    int j = blockIdx.x * 256 + threadIdx.x;
    if (j >= NE) return;
    int2 mt = meta[j];
    int rel = (mt.x >> 17) & 0xFF;
    int q   = (mt.y >> 9) & 0xFF;
    float4 t0 = *(const float4*)(Trel0 + rel * 8);
    float  t4 = Trel0[rel * 8 + 4];
    float4 u0 = *(const float4*)(Tq0 + q * 8);
    float  u4 = Tq0[q * 8 + 4];
    float z = 0.f;
    z = fmaf(fmaxf(t0.x + u0.x, 0.f), W2[0], z);
    z = fmaf(fmaxf(t0.y + u0.y, 0.f), W2[1], z);
    z = fmaf(fmaxf(t0.z + u0.z, 0.f), W2[2], z);
    z = fmaf(fmaxf(t0.w + u0.w, 0.f), W2[3], z);
    z = fmaf(fmaxf(t4   + u4,   0.f), W2[4], z);
    score[j] = 1.f / (1.f + __expf(-z));
}

// ---------------------------------------------------------------------------
// Standalone score for L1/L2 (64 edges/wave — R6 lesson).
__global__ __launch_bounds__(256) void score_kernel(
    const float* __restrict__ proj,     // [NN][8]
    const float* __restrict__ Trel,
    const float* __restrict__ Tq,
    const float* __restrict__ W2,
    const int2* __restrict__ meta,
    float* __restrict__ score)
{
    int j = blockIdx.x * 256 + threadIdx.x;
    if (j >= NE) return;
    int2 mt = meta[j];
    int rel = (mt.x >> 17) & 0xFF;
    int q   = (mt.y >> 9) & 0xFF;
    int src = mt.x & 0x1FFFF;

    float4 t0 = *(const float4*)(Trel + rel * 8);
    float  t4 = Trel[rel * 8 + 4];
    float4 u0 = *(const float4*)(Tq + q * 8);
    float  u4 = Tq[q * 8 + 4];
    float4 p0 = *(const float4*)(proj + (size_t)src * 8);
    float  p4 = proj[(size_t)src * 8 + 4];
    float z = 0.f;
    z = fmaf(fmaxf(p0.x + t0.x + u0.x, 0.f), W2[0], z);
    z = fmaf(fmaxf(p0.y + t0.y + u0.y, 0.f), W2[1], z);
    z = fmaf(fmaxf(p0.z + t0.z + u0.z, 0.f), W2[2], z);
    z = fmaf(fmaxf(p0.w + t0.w + u0.w, 0.f), W2[3], z);
    z = fmaf(fmaxf(p4   + t4   + u4,   0.f), W2[4], z);
    score[j] = 1.f / (1.f + __expf(-z));
}

// ---------------------------------------------------------------------------
// One edge, 8-lane group (lane covers h = hc*8..hc*8+7).
// A[6] = [cls0 h0..3, cls0 h4..7, cls1 lo, cls1 hi, cls2 lo, cls2 hi]
template <bool HZ>
__device__ __forceinline__ void edge1(
    int2 m, float sc, int hc8,
    const ushort* __restrict__ hidden_in,
    const float* __restrict__ rela, const float* __restrict__ temb,
    float4* __restrict__ A)
{
    int src = m.x & 0x1FFFF, rel = (m.x >> 17) & 0xFF;
    int cl  = (m.x >> 25) & 3, ta = m.y & 511;
    const float* rp = rela + rel * HD + hc8;
    const float* tp = temb + ta * HD + hc8;
    float4 rv0 = *(const float4*)rp;
    float4 rv1 = *(const float4*)(rp + 4);
    float4 tv0 = *(const float4*)tp;
    float4 tv1 = *(const float4*)(tp + 4);
    float4 v0, v1;
    v0.x = rv0.x + tv0.x; v0.y = rv0.y + tv0.y;
    v0.z = rv0.z + tv0.z; v0.w = rv0.w + tv0.w;
    v1.x = rv1.x + tv1.x; v1.y = rv1.y + tv1.y;
    v1.z = rv1.z + tv1.z; v1.w = rv1.w + tv1.w;
    if (!HZ) {
        uint4 hv = *(const uint4*)(hidden_in + (size_t)src * HD + hc8);
        v0.x += bflo(hv.x); v0.y += bfhi(hv.x);
        v0.z += bflo(hv.y); v0.w += bfhi(hv.y);
        v1.x += bflo(hv.z); v1.y += bfhi(hv.z);
        v1.z += bflo(hv.w); v1.w += bfhi(hv.w);
    }
    float sA = (cl == 0) ? sc : 0.f;
    float sB = (cl == 1) ? sc : 0.f;
    float sC = (cl == 2) ? sc : 0.f;
    A[0].x = fmaf(sA, v0.x, A[0].x); A[0].y = fmaf(sA, v0.y, A[0].y);
    A[0].z = fmaf(sA, v0.z, A[0].z); A[0].w = fmaf(sA, v0.w, A[0].w);
    A[1].x = fmaf(sA, v1.x, A[1].x); A[1].y = fmaf(sA, v1.y, A[1].y);
    A[1].z = fmaf(sA, v1.z, A[1].z); A[1].w = fmaf(sA, v1.w, A[1].w);
    A[2].x = fmaf(sB, v0.x, A[2].x); A[2].y = fmaf(sB, v0.y, A[2].y);
    A[2].z = fmaf(sB, v0.z, A[2].z); A[2].w = fmaf(sB, v0.w, A[2].w);
    A[3].x = fmaf(sB, v1.x, A[3].x); A[3].y = fmaf(sB, v1.y, A[3].y);
    A[3].z = fmaf(sB, v1.z, A[3].z); A[3].w = fmaf(sB, v1.w, A[3].w);
    A[4].x = fmaf(sC, v0.x, A[4].x); A[4].y = fmaf(sC, v0.y, A[4].y);
    A[4].z = fmaf(sC, v0.z, A[4].z); A[4].w = fmaf(sC, v0.w, A[4].w);
    A[5].x = fmaf(sC, v1.x, A[5].x); A[5].y = fmaf(sC, v1.y, A[5].y);
    A[5].z = fmaf(sC, v1.z, A[5].z); A[5].w = fmaf(sC, v1.w, A[5].w);
}

// ---------------------------------------------------------------------------
// Fused segmented-reduce + MFMA transform + next-layer proj epilogue.
// Edge phase unchanged (8-lane groups, 2x unroll).
// Transform: per class, A slab is packed to LDS as split-bf16 (hi + residual),
// then mfma_f32_16x16x32_bf16 computes D += A_hi*W_hi + A_lo*W_hi + A_hi*W_lo
// (fp19-equivalent precision, fp32 accumulate). Wave w owns node rows
// w*16..w*16+15 x all 64 h (4 n-tiles). D goes through LDS back to the
// original per-lane layout so the store/proj epilogue is unchanged.
// LDS: 64 rows x 68 uints (slab: 32 hi + 32 lo + 4 pad) = 17408 B; the same
// buffer is reused as fp32 D [64][68] and as the proj scratch.
#define SPITCH 68
template <bool HZ, bool PROJ>
__global__ __launch_bounds__(256, 4) void reduce_transform_kernel(
    const ushort* __restrict__ hidden_in,   // bf16 [NN][64]
    const float* __restrict__ rela,         // layer slice [231][64] fp32
    const float* __restrict__ temb,         // [365][64] fp32
    const float* __restrict__ score,        // [E] sorted
    const int2* __restrict__ meta,          // [E] sorted
    const int*  __restrict__ off,           // [NN+1]
    const ushort* __restrict__ WTB,         // bf16 split W frags [3][2][2][4][64][8]
    const float* __restrict__ W1next,       // next layer slice [5][192] (if PROJ)
    ushort* __restrict__ hidden_out,        // bf16 [NN][64]
    float* __restrict__ proj_out)           // [NN][8] (if PROJ)
{
    __shared__ float lds_t[64 * SPITCH];
    int tid  = threadIdx.x;
    int lane = tid & 63;
    int w    = __builtin_amdgcn_readfirstlane(tid >> 6);  // 0..3
    int g    = lane >> 3;                                  // 0..7
    int hc   = lane & 7;                                   // 0..7
    int hc8  = hc * 8;
    int node0 = blockIdx.x * 64;
    int h0 = w * 16;

    float4 a[2][6];
    #pragma unroll
    for (int rr = 0; rr < 2; ++rr)
        #pragma unroll
        for (int c = 0; c < 6; ++c)
            a[rr][c] = make_float4(0.f, 0.f, 0.f, 0.f);

    #pragma unroll
    for (int rr = 0; rr < 2; ++rr) {
        int nl = w * 16 + rr * 8 + g;
        int node = node0 + nl;
        if (node >= NN) continue;
        int o0 = off[node];
        int o1 = off[node + 1];
        int j = o0;
        for (; j + 2 <= o1; j += 2) {
            int2 m0 = meta[j], m1 = meta[j + 1];
            float s0 = score[j], s1 = score[j + 1];
            edge1<HZ>(m0, s0, hc8, hidden_in, rela, temb, a[rr]);
            edge1<HZ>(m1, s1, hc8, hidden_in, rela, temb, a[rr]);
        }
        if (j < o1)
            edge1<HZ>(meta[j], score[j], hc8, hidden_in, rela, temb, a[rr]);
    }

    // --- transform via split-bf16 MFMA, one class slab at a time ---
    unsigned* lds_u = (unsigned*)lds_t;
    int rl = lane & 15;
    int t  = lane >> 4;
    f32x4 accd[4];
    #pragma unroll
    for (int nt = 0; nt < 4; ++nt)
        accd[nt] = (f32x4){0.f, 0.f, 0.f, 0.f};

    #pragma unroll
    for (int c = 0; c < 3; ++c) {
        __syncthreads();   // protect previous slab's reads
        #pragma unroll
        for (int rr = 0; rr < 2; ++rr) {
            int nl = w * 16 + rr * 8 + g;
            float4 v0 = a[rr][2 * c];
            float4 v1 = a[rr][2 * c + 1];
            unsigned p0 = packbf2(v0.x, v0.y);
            unsigned p1 = packbf2(v0.z, v0.w);
            unsigned p2 = packbf2(v1.x, v1.y);
            unsigned p3 = packbf2(v1.z, v1.w);
            unsigned q0 = packbf2(v0.x - bflo(p0), v0.y - bfhi(p0));
            unsigned q1 = packbf2(v0.z - bflo(p1), v0.w - bfhi(p1));
            unsigned q2 = packbf2(v1.x - bflo(p2), v1.y - bfhi(p2));
            unsigned q3 = packbf2(v1.z - bflo(p3), v1.w - bfhi(p3));
            *(uint4*)(lds_u + nl * SPITCH + hc * 4)      = make_uint4(p0, p1, p2, p3);
            *(uint4*)(lds_u + nl * SPITCH + 32 + hc * 4) = make_uint4(q0, q1, q2, q3);
        }
        __syncthreads();
        #pragma unroll
        for (int ks = 0; ks < 2; ++ks) {
            const unsigned* rowp = lds_u + (w * 16 + rl) * SPITCH + ks * 16 + t * 4;
            vbf8 ah = *(const vbf8*)rowp;
            vbf8 al = *(const vbf8*)(rowp + 32);
            #pragma unroll
            for (int nt = 0; nt < 4; ++nt) {
                const ushort* bp = WTB +
                    (size_t)((((c * 2) * 2 + ks) * 4 + nt) * 64 + lane) * 8;
                vbf8 bh = *(const vbf8*)bp;
                vbf8 bl = *(const vbf8*)(bp + 4096);   // hl=1 plane
                accd[nt] = __builtin_amdgcn_mfma_f32_16x16x32_bf16(ah, bh, accd[nt], 0, 0, 0);
                accd[nt] = __builtin_amdgcn_mfma_f32_16x16x32_bf16(al, bh, accd[nt], 0, 0, 0);
                accd[nt] = __builtin_amdgcn_mfma_f32_16x16x32_bf16(ah, bl, accd[nt], 0, 0, 0);
            }
        }
    }

    // D frag (col=lane&15, row=(lane>>4)*4+i) -> LDS [node][h] fp32
    __syncthreads();
    #pragma unroll
    for (int nt = 0; nt < 4; ++nt)
        #pragma unroll
        for (int i = 0; i < 4; ++i)
            lds_t[(w * 16 + t * 4 + i) * SPITCH + nt * 16 + rl] = accd[nt][i];
    __syncthreads();

    // back to the original per-lane layout: lane owns node node0+lane, h slice h0..h0+15
    float acc[16];
    {
        const float4* rp = (const float4*)(lds_t + lane * SPITCH + h0);
        #pragma unroll
        for (int i4 = 0; i4 < 4; ++i4) {
            float4 v = rp[i4];
            acc[i4 * 4 + 0] = v.x; acc[i4 * 4 + 1] = v.y;
            acc[i4 * 4 + 2] = v.z; acc[i4 * 4 + 3] = v.w;
        }
    }

    int node = node0 + lane;
    if (node < NN) {
        ushort* outp = hidden_out + (size_t)node * 64 + h0;
        unsigned up[8];
        #pragma unroll
        for (int p = 0; p < 8; ++p)
            up[p] = packbf2(fmaxf(acc[2 * p], 0.f), fmaxf(acc[2 * p + 1], 0.f));
        *(uint4*)(outp)     = make_uint4(up[0], up[1], up[2], up[3]);
        *(uint4*)(outp + 8) = make_uint4(up[4], up[5], up[6], up[7]);
    }

    // --- epilogue: proj for NEXT layer from fp32 acc (exact) ---
    if (PROJ) {
        float pa[AD];
        #pragma unroll
        for (int aa = 0; aa < AD; ++aa) pa[aa] = 0.f;
        #pragma unroll
        for (int i = 0; i < 16; ++i) {
            float hv = fmaxf(acc[i], 0.f);
            #pragma unroll
            for (int aa = 0; aa < AD; ++aa)
                pa[aa] = fmaf(hv, W1next[aa * 192 + h0 + i], pa[aa]);
        }
        __syncthreads();
        float* lds2 = lds_t;   // reuse as [4][64][5]
        #pragma unroll
        for (int aa = 0; aa < AD; ++aa)
            lds2[(w * 64 + lane) * AD + aa] = pa[aa];
        __syncthreads();
        for (int idx = tid; idx < 64 * 8; idx += 256) {
            int nd = idx >> 3, aa = idx & 7;
            if (node0 + nd >= NN) break;
            float v = 0.f;
            if (aa < AD) {
                #pragma unroll
                for (int w4 = 0; w4 < 4; ++w4)
                    v += lds2[(w4 * 64 + nd) * AD + aa];
            }
            proj_out[(size_t)(node0 + nd) * 8 + aa] = v;
        }
    }
}

// ---------------------------------------------------------------------------
__global__ __launch_bounds__(256) void out_kernel(
    const ushort* __restrict__ hidden,   // bf16 [NN][64]
    const float* __restrict__ Wc,
    const float* __restrict__ bc,
    float* __restrict__ out)
{
    int i = blockIdx.x * 256 + threadIdx.x;
    if (i >= NOUT) return;
    float r = 0.f;
    if (i < NN) {
        const uint4* h4 = (const uint4*)(hidden + (size_t)i * 64);
        float acc = 0.f;
        #pragma unroll
        for (int q = 0; q < 8; ++q) {
            uint4 hv = h4[q];
            const float* wq = Wc + q * 8;
            acc = fmaf(bflo(hv.x), wq[0], acc);
            acc = fmaf(bfhi(hv.x), wq[1], acc);
            acc = fmaf(bflo(hv.y), wq[2], acc);
            acc = fmaf(bfhi(hv.y), wq[3], acc);
            acc = fmaf(bflo(hv.z), wq[4], acc);
            acc = fmaf(bfhi(hv.z), wq[5], acc);
            acc = fmaf(bflo(hv.w), wq[6], acc);
            acc = fmaf(bfhi(hv.w), wq[7], acc);
        }
        r = acc + bc[0];
    }
    out[i] = r;
}

// ---------------------------------------------------------------------------
extern "C" void kernel_launch(void* const* d_in, const int* in_sizes, int n_in,
                              void* d_out, int out_size, void* d_ws, size_t ws_size,
                              hipStream_t stream)
{
    const int*   batch_idx  = (const int*)d_in[0];
    const int*   src_idx    = (const int*)d_in[1];
    const int*   dst_idx    = (const int*)d_in[2];
    const int*   rel_idx    = (const int*)d_in[3];
    const int*   rel_time   = (const int*)d_in[4];
    const int*   query_rel  = (const int*)d_in[5];
    const float* rela_embed = (const float*)d_in[8];   // [3][231][64]
    const float* time_embed = (const float*)d_in[9];   // [365][64]
    const float* Wp         = (const float*)d_in[10];
    const float* Wn         = (const float*)d_in[11];
    const float* Wf         = (const float*)d_in[12];
    const float* W1         = (const float*)d_in[13];  // [3][5][192]
    const float* W2         = (const float*)d_in[14];  // [3][1][5]
    const float* Wc         = (const float*)d_in[15];  // [64]
    const float* bc         = (const float*)d_in[16];  // [1]
    float* out = (float*)d_out;

    char* ws = (char*)d_ws;
    ushort* hid0  = (ushort*)(ws + 0);           // 12.8 MB bf16
    ushort* hid1  = (ushort*)(ws + 12800000);    // 12.8 MB bf16
    float* projA  = (float*)(ws + 25600000);     //  3.2 MB
    float* projB  = (float*)(ws + 28800000);     //  3.2 MB
    float* score  = (float*)(ws + 32000000);     //  4.0 MB
    ushort* WTB   = (ushort*)(ws + 36000000);    //  48 KB bf16 split W frags
    float* Trel   = (float*)(ws + 36100000);     //  ~22 KB
    float* Tq     = (float*)(ws + 36130000);     //  ~22 KB
    int*   off    = (int*)  (ws + 36160000);     // 400 KB (NN+1)
    int2*  meta   = (int2*) (ws + 37400000);     //  8.0 MB
    int*   deg    = (int*)  (ws + 45400000);     // 400 KB
    int*   tmp    = (int*)  (ws + 46600000);     // 400 KB
    int*   cursor = (int*)  (ws + 47800000);     // 400 KB
    int*   bsum   = (int*)  (ws + 49000000);     //  ~2 KB
    int*   bpref  = (int*)  (ws + 49010000);     //  ~2 KB

    prep_wtb_kernel<<<12, 256, 0, stream>>>(Wp, Wn, Wf, WTB);
    prep_tables_kernel<<<NL, 256, 0, stream>>>(rela_embed, W1, Trel, Tq);

    // --- counting sort by dst ---
    hipMemsetAsync(deg, 0, NN * sizeof(int), stream);
    hist_kernel<<<(NE + 255) / 256, 256, 0, stream>>>(dst_idx, deg);
    scan1_kernel<<<NBLK1, 256, 0, stream>>>(deg, tmp, bsum);
    scan2_kernel<<<1, 512, 0, stream>>>(bsum, bpref);
    scan3_kernel<<<NBLK1, 256, 0, stream>>>(deg, tmp, bpref, off, cursor);
    sort_scatter_kernel<<<(NE + 255) / 256, 256, 0, stream>>>(
        dst_idx, src_idx, rel_idx, rel_time, batch_idx, query_rel,
        cursor, meta);
    // layer-0 score: linear fill from sorted meta (coalesced read+write)
    score0_lin_kernel<<<(NE + 255) / 256, 256, 0, stream>>>(
        meta, Trel, Tq, W2, score);

    // --- layers: L0 -> hid0/projA ; L1 hid0,projA -> hid1/projB ;
    //             L2 hid1,projB -> hid0 ---
    int grid = (NN + 63) / 64;
    int sgrid = (NE + 255) / 256;
    {
        reduce_transform_kernel<true, true><<<grid, 256, 0, stream>>>(
            hid1, rela_embed, time_embed, score, meta, off,
            WTB, W1 + (size_t)1 * AD * 192, hid0, projA);
    }
    {
        const float* rela = rela_embed + (size_t)1 * NRL * HD;
        score_kernel<<<sgrid, 256, 0, stream>>>(
            projA, Trel + (size_t)1 * NRL * 8, Tq + (size_t)1 * NRL * 8,
            W2 + 1 * AD, meta, score);
        reduce_transform_kernel<false, true><<<grid, 256, 0, stream>>>(
            hid0, rela, time_embed, score, meta, off,
            WTB, W1 + (size_t)2 * AD * 192, hid1, projB);
    }
    {
        const float* rela = rela_embed + (size_t)2 * NRL * HD;
        score_kernel<<<sgrid, 256, 0, stream>>>(
            projB, Trel + (size_t)2 * NRL * 8, Tq + (size_t)2 * NRL * 8,
            W2 + 2 * AD, meta, score);
        reduce_transform_kernel<false, false><<<grid, 256, 0, stream>>>(
            hid1, rela, time_embed, score, meta, off,
            WTB, nullptr, hid0, nullptr);
    }

    out_kernel<<<(NOUT + 255) / 256, 256, 0, stream>>>(hid0, Wc, bc, out);
}

// Round 5
// 397.792 us; speedup vs baseline: 1.0948x; 1.0948x over previous
//
#include <hip/hip_runtime.h>

#define NB   32
#define NN   100000
#define NE   1000000
#define HD   64
#define AD   5
#define NL   3
#define NRL  231      // N_REL + 1
#define NTM  365
#define NOUT 228096   // 32 * 7128
#define NBLK1 391     // ceil(NN/256)

// meta packing: w0 = src | (rel<<17) | (cls<<25) ; w1 = ta | (q<<9)

// bf16 helpers (hidden stored as bf16 to halve gather traffic)
__device__ __forceinline__ float bflo(unsigned u) { return __uint_as_float(u << 16); }
__device__ __forceinline__ float bfhi(unsigned u) { return __uint_as_float(u & 0xffff0000u); }
__device__ __forceinline__ unsigned packbf2(float x, float y) {
    unsigned ux = __float_as_uint(x), uy = __float_as_uint(y);
    ux = (ux + 0x7fffu + ((ux >> 16) & 1u)) >> 16;
    uy = (uy + 0x7fffu + ((uy >> 16) & 1u)) >> 16;
    return ux | (uy << 16);
}

using vbf8  = __attribute__((ext_vector_type(8))) short;   // 8 bf16 (4 VGPRs) MFMA A/B frag
using f32x4 = __attribute__((ext_vector_type(4))) float;   // MFMA C/D frag

// ---------------------------------------------------------------------------
// WTB: W in bf16 split (hi/lo) laid out as MFMA B-fragments.
// flat idx = ((((c*2 + hl)*2 + ks)*4 + nt)*64 + lane)*8 ushorts
// value(lane, j) = W_c[h = nt*16 + (lane&15)][k = ks*32 + (lane>>4)*8 + j]
// c: 0=Wf(pos) 1=Wn(zero) 2=Wp(neg); hl: 0=hi 1=residual
__global__ __launch_bounds__(256) void prep_wtb_kernel(
    const float* __restrict__ Wp, const float* __restrict__ Wn,
    const float* __restrict__ Wf, ushort* __restrict__ WTB)
{
    int i = blockIdx.x * 256 + threadIdx.x;
    if (i >= 3072) return;
    int lane = i & 63;
    int nt = (i >> 6) & 3;
    int ks = (i >> 8) & 1;
    int hl = (i >> 9) & 1;
    int c  = i >> 10;
    const float* W = (c == 0) ? Wf : (c == 1 ? Wn : Wp);
    int h  = nt * 16 + (lane & 15);
    int k0 = ks * 32 + (lane >> 4) * 8;
    unsigned up[4];
    #pragma unroll
    for (int j = 0; j < 4; ++j) {
        float x = W[h * 64 + k0 + 2 * j];
        float y = W[h * 64 + k0 + 2 * j + 1];
        unsigned pb = packbf2(x, y);
        if (hl) {
            float rx = x - bflo(pb);
            float ry = y - bfhi(pb);
            pb = packbf2(rx, ry);
        }
        up[j] = pb;
    }
    *(uint4*)(WTB + (size_t)i * 8) = make_uint4(up[0], up[1], up[2], up[3]);
}

// ---------------------------------------------------------------------------
__global__ __launch_bounds__(256) void prep_tables_kernel(
    const float* __restrict__ rela_embed,   // [3][231][64]
    const float* __restrict__ W1,           // [3][5][192]
    float* __restrict__ Trel,               // [3][231][8]
    float* __restrict__ Tq)                 // [3][231][8]
{
    int l = blockIdx.x;
    int r = threadIdx.x;
    if (r >= NRL) return;
    const float4* rrow = (const float4*)(rela_embed + ((size_t)l * NRL + r) * HD);
    const float* W1l = W1 + (size_t)l * AD * 192;
    float tr[AD] = {0,0,0,0,0}, tq[AD] = {0,0,0,0,0};
    #pragma unroll
    for (int k4 = 0; k4 < 16; ++k4) {
        float4 x = rrow[k4];
        #pragma unroll
        for (int a = 0; a < AD; ++a) {
            const float* wr = W1l + a * 192 + 64 + k4 * 4;
            const float* wq = W1l + a * 192 + 128 + k4 * 4;
            tr[a] = fmaf(x.x, wr[0], tr[a]); tr[a] = fmaf(x.y, wr[1], tr[a]);
            tr[a] = fmaf(x.z, wr[2], tr[a]); tr[a] = fmaf(x.w, wr[3], tr[a]);
            tq[a] = fmaf(x.x, wq[0], tq[a]); tq[a] = fmaf(x.y, wq[1], tq[a]);
            tq[a] = fmaf(x.z, wq[2], tq[a]); tq[a] = fmaf(x.w, wq[3], tq[a]);
        }
    }
    float* tro = Trel + ((size_t)l * NRL + r) * 8;
    float* tqo = Tq   + ((size_t)l * NRL + r) * 8;
    #pragma unroll
    for (int a = 0; a < AD; ++a) { tro[a] = tr[a]; tqo[a] = tq[a]; }
    tro[5] = tro[6] = tro[7] = 0.f;
    tqo[5] = tqo[6] = tqo[7] = 0.f;
}

// ---------------------------------------------------------------------------
// Counting sort by dst (dst-only: long segments keep MLP alive — R8 lesson).
// hist also captures each edge's rank within its dst bucket (the atomicAdd
// return we used to discard). The rank store is coalesced fire-and-forget,
// so hist doesn't stall; the scatter then needs NO atomic at all.
__global__ __launch_bounds__(256) void hist_kernel(
    const int* __restrict__ dst_idx, int* __restrict__ deg,
    ushort* __restrict__ rank)
{
    int e = blockIdx.x * 256 + threadIdx.x;
    if (e < NE) rank[e] = (ushort)atomicAdd(&deg[dst_idx[e]], 1);
}

__global__ __launch_bounds__(256) void scan1_kernel(
    const int* __restrict__ deg, int* __restrict__ tmp, int* __restrict__ bsum)
{
    __shared__ int s[256];
    int tid = threadIdx.x;
    int i = blockIdx.x * 256 + tid;
    int v = (i < NN) ? deg[i] : 0;
    s[tid] = v;
    __syncthreads();
    #pragma unroll
    for (int st = 1; st < 256; st <<= 1) {
        int t = (tid >= st) ? s[tid - st] : 0;
        __syncthreads();
        s[tid] += t;
        __syncthreads();
    }
    if (i < NN) tmp[i] = s[tid];
    if (tid == 255) bsum[blockIdx.x] = s[255];
}

__global__ __launch_bounds__(512) void scan2_kernel(
    const int* __restrict__ bsum, int* __restrict__ bpref)
{
    __shared__ int s[512];
    int tid = threadIdx.x;
    int v = (tid < NBLK1) ? bsum[tid] : 0;
    s[tid] = v;
    __syncthreads();
    #pragma unroll
    for (int st = 1; st < 512; st <<= 1) {
        int t = (tid >= st) ? s[tid - st] : 0;
        __syncthreads();
        s[tid] += t;
        __syncthreads();
    }
    if (tid < NBLK1) bpref[tid] = s[tid] - v;  // exclusive
}

__global__ __launch_bounds__(256) void scan3_kernel(
    const int* __restrict__ deg, const int* __restrict__ tmp,
    const int* __restrict__ bpref, int* __restrict__ off)
{
    int i = blockIdx.x * 256 + threadIdx.x;
    if (i >= NN) return;
    int incl = tmp[i] + bpref[i >> 8];
    off[i + 1] = incl;
    if (i == 0) off[0] = 0;
}

// scatter into dst-sorted order, ATOMIC-FREE: pos = off[d] + rank[e].
// off[d] is a plain cacheable read (400 KB, L1/L2-hot) — no per-address
// serialization, no RMW round trip (R3 lesson: the atomic return was the
// latency chain; the random stores themselves are fire-and-forget, so the
// layer-0 score scatter rides along for free).
__global__ __launch_bounds__(256) void sort_scatter_kernel(
    const int* __restrict__ dst_idx, const int* __restrict__ src_idx,
    const int* __restrict__ rel_idx, const int* __restrict__ rel_time,
    const int* __restrict__ batch_idx, const int* __restrict__ query_rel,
    const int* __restrict__ off, const ushort* __restrict__ rank,
    const float* __restrict__ Trel0, const float* __restrict__ Tq0,
    const float* __restrict__ W2,
    int2* __restrict__ meta, float* __restrict__ score0)
{
    int e = blockIdx.x * 256 + threadIdx.x;
    if (e >= NE) return;
    int d = dst_idx[e];
    int rt = rel_time[e];
    int cls = (rt > 0) ? 0 : ((rt == 0) ? 1 : 2);
    int ta = (rt < 0) ? -rt : rt;
    int rel = rel_idx[e];
    int q = query_rel[batch_idx[e]];
    int pos = off[d] + (int)rank[e];
    int2 m;
    m.x = src_idx[e] | (rel << 17) | (cls << 25);
    m.y = ta | (q << 9);
    meta[pos] = m;

    float4 t0 = *(const float4*)(Trel0 + rel * 8);
    float  t4 = Trel0[rel * 8 + 4];
    float4 u0 = *(const float4*)(Tq0 + q * 8);
    float  u4 = Tq0[q * 8 + 4];
    float z = 0.f;
    z = fmaf(fmaxf(t0.x + u0.x, 0.f), W2[0], z);
    z = fmaf(fmaxf(t0.y + u0.y, 0.f), W2[1], z);
    z = fmaf(fmaxf(t0.z + u0.z, 0.f), W2[2], z);
    z = fmaf(fmaxf(t0.w + u0.w, 0.f), W2[3], z);
    z = fmaf(fmaxf(t4   + u4,   0.f), W2[4], z);
    score0[pos] = 1.f / (1.f + __expf(-z));
}

// ---------------------------------------------------------------------------
// Standalone score for L1/L2 (64 edges/wave — R6 lesson).
__global__ __launch_bounds__(256) void score_kernel(
    const float* __restrict__ proj,     // [NN][8]
    const float* __restrict__ Trel,
    const float* __restrict__ Tq,
    const float* __restrict__ W2,
    const int2* __restrict__ meta,
    float* __restrict__ score)
{
    int j = blockIdx.x * 256 + threadIdx.x;
    if (j >= NE) return;
    int2 mt = meta[j];
    int rel = (mt.x >> 17) & 0xFF;
    int q   = (mt.y >> 9) & 0xFF;
    int src = mt.x & 0x1FFFF;

    float4 t0 = *(const float4*)(Trel + rel * 8);
    float  t4 = Trel[rel * 8 + 4];
    float4 u0 = *(const float4*)(Tq + q * 8);
    float  u4 = Tq[q * 8 + 4];
    float4 p0 = *(const float4*)(proj + (size_t)src * 8);
    float  p4 = proj[(size_t)src * 8 + 4];
    float z = 0.f;
    z = fmaf(fmaxf(p0.x + t0.x + u0.x, 0.f), W2[0], z);
    z = fmaf(fmaxf(p0.y + t0.y + u0.y, 0.f), W2[1], z);
    z = fmaf(fmaxf(p0.z + t0.z + u0.z, 0.f), W2[2], z);
    z = fmaf(fmaxf(p0.w + t0.w + u0.w, 0.f), W2[3], z);
    z = fmaf(fmaxf(p4   + t4   + u4,   0.f), W2[4], z);
    score[j] = 1.f / (1.f + __expf(-z));
}

// ---------------------------------------------------------------------------
// One edge, 8-lane group (lane covers h = hc*8..hc*8+7).
// A[6] = [cls0 h0..3, cls0 h4..7, cls1 lo, cls1 hi, cls2 lo, cls2 hi]
template <bool HZ>
__device__ __forceinline__ void edge1(
    int2 m, float sc, int hc8,
    const ushort* __restrict__ hidden_in,
    const float* __restrict__ rela, const float* __restrict__ temb,
    float4* __restrict__ A)
{
    int src = m.x & 0x1FFFF, rel = (m.x >> 17) & 0xFF;
    int cl  = (m.x >> 25) & 3, ta = m.y & 511;
    const float* rp = rela + rel * HD + hc8;
    const float* tp = temb + ta * HD + hc8;
    float4 rv0 = *(const float4*)rp;
    float4 rv1 = *(const float4*)(rp + 4);
    float4 tv0 = *(const float4*)tp;
    float4 tv1 = *(const float4*)(tp + 4);
    float4 v0, v1;
    v0.x = rv0.x + tv0.x; v0.y = rv0.y + tv0.y;
    v0.z = rv0.z + tv0.z; v0.w = rv0.w + tv0.w;
    v1.x = rv1.x + tv1.x; v1.y = rv1.y + tv1.y;
    v1.z = rv1.z + tv1.z; v1.w = rv1.w + tv1.w;
    if (!HZ) {
        uint4 hv = *(const uint4*)(hidden_in + (size_t)src * HD + hc8);
        v0.x += bflo(hv.x); v0.y += bfhi(hv.x);
        v0.z += bflo(hv.y); v0.w += bfhi(hv.y);
        v1.x += bflo(hv.z); v1.y += bfhi(hv.z);
        v1.z += bflo(hv.w); v1.w += bfhi(hv.w);
    }
    float sA = (cl == 0) ? sc : 0.f;
    float sB = (cl == 1) ? sc : 0.f;
    float sC = (cl == 2) ? sc : 0.f;
    A[0].x = fmaf(sA, v0.x, A[0].x); A[0].y = fmaf(sA, v0.y, A[0].y);
    A[0].z = fmaf(sA, v0.z, A[0].z); A[0].w = fmaf(sA, v0.w, A[0].w);
    A[1].x = fmaf(sA, v1.x, A[1].x); A[1].y = fmaf(sA, v1.y, A[1].y);
    A[1].z = fmaf(sA, v1.z, A[1].z); A[1].w = fmaf(sA, v1.w, A[1].w);
    A[2].x = fmaf(sB, v0.x, A[2].x); A[2].y = fmaf(sB, v0.y, A[2].y);
    A[2].z = fmaf(sB, v0.z, A[2].z); A[2].w = fmaf(sB, v0.w, A[2].w);
    A[3].x = fmaf(sB, v1.x, A[3].x); A[3].y = fmaf(sB, v1.y, A[3].y);
    A[3].z = fmaf(sB, v1.z, A[3].z); A[3].w = fmaf(sB, v1.w, A[3].w);
    A[4].x = fmaf(sC, v0.x, A[4].x); A[4].y = fmaf(sC, v0.y, A[4].y);
    A[4].z = fmaf(sC, v0.z, A[4].z); A[4].w = fmaf(sC, v0.w, A[4].w);
    A[5].x = fmaf(sC, v1.x, A[5].x); A[5].y = fmaf(sC, v1.y, A[5].y);
    A[5].z = fmaf(sC, v1.z, A[5].z); A[5].w = fmaf(sC, v1.w, A[5].w);
}

// ---------------------------------------------------------------------------
// Fused segmented-reduce + MFMA transform + next-layer proj epilogue.
// Edge phase unchanged (8-lane groups, 2x unroll).
// Transform: per class, A slab is packed to LDS as split-bf16 (hi + residual),
// then mfma_f32_16x16x32_bf16 computes D += A_hi*W_hi + A_lo*W_hi + A_hi*W_lo
// (fp19-equivalent precision, fp32 accumulate). Wave w owns node rows
// w*16..w*16+15 x all 64 h (4 n-tiles). D goes through LDS back to the
// original per-lane layout so the store/proj epilogue is unchanged.
// LDS: 64 rows x 68 uints (slab: 32 hi + 32 lo + 4 pad) = 17408 B; the same
// buffer is reused as fp32 D [64][68] and as the proj scratch.
#define SPITCH 68
template <bool HZ, bool PROJ>
__global__ __launch_bounds__(256, 4) void reduce_transform_kernel(
    const ushort* __restrict__ hidden_in,   // bf16 [NN][64]
    const float* __restrict__ rela,         // layer slice [231][64] fp32
    const float* __restrict__ temb,         // [365][64] fp32
    const float* __restrict__ score,        // [E] sorted
    const int2* __restrict__ meta,          // [E] sorted
    const int*  __restrict__ off,           // [NN+1]
    const ushort* __restrict__ WTB,         // bf16 split W frags [3][2][2][4][64][8]
    const float* __restrict__ W1next,       // next layer slice [5][192] (if PROJ)
    ushort* __restrict__ hidden_out,        // bf16 [NN][64]
    float* __restrict__ proj_out)           // [NN][8] (if PROJ)
{
    __shared__ float lds_t[64 * SPITCH];
    int tid  = threadIdx.x;
    int lane = tid & 63;
    int w    = __builtin_amdgcn_readfirstlane(tid >> 6);  // 0..3
    int g    = lane >> 3;                                  // 0..7
    int hc   = lane & 7;                                   // 0..7
    int hc8  = hc * 8;
    int node0 = blockIdx.x * 64;
    int h0 = w * 16;

    float4 a[2][6];
    #pragma unroll
    for (int rr = 0; rr < 2; ++rr)
        #pragma unroll
        for (int c = 0; c < 6; ++c)
            a[rr][c] = make_float4(0.f, 0.f, 0.f, 0.f);

    #pragma unroll
    for (int rr = 0; rr < 2; ++rr) {
        int nl = w * 16 + rr * 8 + g;
        int node = node0 + nl;
        if (node >= NN) continue;
        int o0 = off[node];
        int o1 = off[node + 1];
        int j = o0;
        for (; j + 2 <= o1; j += 2) {
            int2 m0 = meta[j], m1 = meta[j + 1];
            float s0 = score[j], s1 = score[j + 1];
            edge1<HZ>(m0, s0, hc8, hidden_in, rela, temb, a[rr]);
            edge1<HZ>(m1, s1, hc8, hidden_in, rela, temb, a[rr]);
        }
        if (j < o1)
            edge1<HZ>(meta[j], score[j], hc8, hidden_in, rela, temb, a[rr]);
    }

    // --- transform via split-bf16 MFMA, one class slab at a time ---
    unsigned* lds_u = (unsigned*)lds_t;
    int rl = lane & 15;
    int t  = lane >> 4;
    f32x4 accd[4];
    #pragma unroll
    for (int nt = 0; nt < 4; ++nt)
        accd[nt] = (f32x4){0.f, 0.f, 0.f, 0.f};

    #pragma unroll
    for (int c = 0; c < 3; ++c) {
        __syncthreads();   // protect previous slab's reads
        #pragma unroll
        for (int rr = 0; rr < 2; ++rr) {
            int nl = w * 16 + rr * 8 + g;
            float4 v0 = a[rr][2 * c];
            float4 v1 = a[rr][2 * c + 1];
            unsigned p0 = packbf2(v0.x, v0.y);
            unsigned p1 = packbf2(v0.z, v0.w);
            unsigned p2 = packbf2(v1.x, v1.y);
            unsigned p3 = packbf2(v1.z, v1.w);
            unsigned q0 = packbf2(v0.x - bflo(p0), v0.y - bfhi(p0));
            unsigned q1 = packbf2(v0.z - bflo(p1), v0.w - bfhi(p1));
            unsigned q2 = packbf2(v1.x - bflo(p2), v1.y - bfhi(p2));
            unsigned q3 = packbf2(v1.z - bflo(p3), v1.w - bfhi(p3));
            *(uint4*)(lds_u + nl * SPITCH + hc * 4)      = make_uint4(p0, p1, p2, p3);
            *(uint4*)(lds_u + nl * SPITCH + 32 + hc * 4) = make_uint4(q0, q1, q2, q3);
        }
        __syncthreads();
        #pragma unroll
        for (int ks = 0; ks < 2; ++ks) {
            const unsigned* rowp = lds_u + (w * 16 + rl) * SPITCH + ks * 16 + t * 4;
            vbf8 ah = *(const vbf8*)rowp;
            vbf8 al = *(const vbf8*)(rowp + 32);
            #pragma unroll
            for (int nt = 0; nt < 4; ++nt) {
                const ushort* bp = WTB +
                    (size_t)((((c * 2) * 2 + ks) * 4 + nt) * 64 + lane) * 8;
                vbf8 bh = *(const vbf8*)bp;
                vbf8 bl = *(const vbf8*)(bp + 4096);   // hl=1 plane
                accd[nt] = __builtin_amdgcn_mfma_f32_16x16x32_bf16(ah, bh, accd[nt], 0, 0, 0);
                accd[nt] = __builtin_amdgcn_mfma_f32_16x16x32_bf16(al, bh, accd[nt], 0, 0, 0);
                accd[nt] = __builtin_amdgcn_mfma_f32_16x16x32_bf16(ah, bl, accd[nt], 0, 0, 0);
            }
        }
    }

    // D frag (col=lane&15, row=(lane>>4)*4+i) -> LDS [node][h] fp32
    __syncthreads();
    #pragma unroll
    for (int nt = 0; nt < 4; ++nt)
        #pragma unroll
        for (int i = 0; i < 4; ++i)
            lds_t[(w * 16 + t * 4 + i) * SPITCH + nt * 16 + rl] = accd[nt][i];
    __syncthreads();

    // back to the original per-lane layout: lane owns node node0+lane, h slice h0..h0+15
    float acc[16];
    {
        const float4* rp = (const float4*)(lds_t + lane * SPITCH + h0);
        #pragma unroll
        for (int i4 = 0; i4 < 4; ++i4) {
            float4 v = rp[i4];
            acc[i4 * 4 + 0] = v.x; acc[i4 * 4 + 1] = v.y;
            acc[i4 * 4 + 2] = v.z; acc[i4 * 4 + 3] = v.w;
        }
    }

    int node = node0 + lane;
    if (node < NN) {
        ushort* outp = hidden_out + (size_t)node * 64 + h0;
        unsigned up[8];
        #pragma unroll
        for (int p = 0; p < 8; ++p)
            up[p] = packbf2(fmaxf(acc[2 * p], 0.f), fmaxf(acc[2 * p + 1], 0.f));
        *(uint4*)(outp)     = make_uint4(up[0], up[1], up[2], up[3]);
        *(uint4*)(outp + 8) = make_uint4(up[4], up[5], up[6], up[7]);
    }

    // --- epilogue: proj for NEXT layer from fp32 acc (exact) ---
    if (PROJ) {
        float pa[AD];
        #pragma unroll
        for (int aa = 0; aa < AD; ++aa) pa[aa] = 0.f;
        #pragma unroll
        for (int i = 0; i < 16; ++i) {
            float hv = fmaxf(acc[i], 0.f);
            #pragma unroll
            for (int aa = 0; aa < AD; ++aa)
                pa[aa] = fmaf(hv, W1next[aa * 192 + h0 + i], pa[aa]);
        }
        __syncthreads();
        float* lds2 = lds_t;   // reuse as [4][64][5]
        #pragma unroll
        for (int aa = 0; aa < AD; ++aa)
            lds2[(w * 64 + lane) * AD + aa] = pa[aa];
        __syncthreads();
        for (int idx = tid; idx < 64 * 8; idx += 256) {
            int nd = idx >> 3, aa = idx & 7;
            if (node0 + nd >= NN) break;
            float v = 0.f;
            if (aa < AD) {
                #pragma unroll
                for (int w4 = 0; w4 < 4; ++w4)
                    v += lds2[(w4 * 64 + nd) * AD + aa];
            }
            proj_out[(size_t)(node0 + nd) * 8 + aa] = v;
        }
    }
}

// ---------------------------------------------------------------------------
__global__ __launch_bounds__(256) void out_kernel(
    const ushort* __restrict__ hidden,   // bf16 [NN][64]
    const float* __restrict__ Wc,
    const float* __restrict__ bc,
    float* __restrict__ out)
{
    int i = blockIdx.x * 256 + threadIdx.x;
    if (i >= NOUT) return;
    float r = 0.f;
    if (i < NN) {
        const uint4* h4 = (const uint4*)(hidden + (size_t)i * 64);
        float acc = 0.f;
        #pragma unroll
        for (int q = 0; q < 8; ++q) {
            uint4 hv = h4[q];
            const float* wq = Wc + q * 8;
            acc = fmaf(bflo(hv.x), wq[0], acc);
            acc = fmaf(bfhi(hv.x), wq[1], acc);
            acc = fmaf(bflo(hv.y), wq[2], acc);
            acc = fmaf(bfhi(hv.y), wq[3], acc);
            acc = fmaf(bflo(hv.z), wq[4], acc);
            acc = fmaf(bfhi(hv.z), wq[5], acc);
            acc = fmaf(bflo(hv.w), wq[6], acc);
            acc = fmaf(bfhi(hv.w), wq[7], acc);
        }
        r = acc + bc[0];
    }
    out[i] = r;
}

// ---------------------------------------------------------------------------
extern "C" void kernel_launch(void* const* d_in, const int* in_sizes, int n_in,
                              void* d_out, int out_size, void* d_ws, size_t ws_size,
                              hipStream_t stream)
{
    const int*   batch_idx  = (const int*)d_in[0];
    const int*   src_idx    = (const int*)d_in[1];
    const int*   dst_idx    = (const int*)d_in[2];
    const int*   rel_idx    = (const int*)d_in[3];
    const int*   rel_time   = (const int*)d_in[4];
    const int*   query_rel  = (const int*)d_in[5];
    const float* rela_embed = (const float*)d_in[8];   // [3][231][64]
    const float* time_embed = (const float*)d_in[9];   // [365][64]
    const float* Wp         = (const float*)d_in[10];
    const float* Wn         = (const float*)d_in[11];
    const float* Wf         = (const float*)d_in[12];
    const float* W1         = (const float*)d_in[13];  // [3][5][192]
    const float* W2         = (const float*)d_in[14];  // [3][1][5]
    const float* Wc         = (const float*)d_in[15];  // [64]
    const float* bc         = (const float*)d_in[16];  // [1]
    float* out = (float*)d_out;

    char* ws = (char*)d_ws;
    ushort* hid0  = (ushort*)(ws + 0);           // 12.8 MB bf16
    ushort* hid1  = (ushort*)(ws + 12800000);    // 12.8 MB bf16
    float* projA  = (float*)(ws + 25600000);     //  3.2 MB
    float* projB  = (float*)(ws + 28800000);     //  3.2 MB
    float* score  = (float*)(ws + 32000000);     //  4.0 MB
    ushort* WTB   = (ushort*)(ws + 36000000);    //  48 KB bf16 split W frags
    float* Trel   = (float*)(ws + 36100000);     //  ~22 KB
    float* Tq     = (float*)(ws + 36130000);     //  ~22 KB
    int*   off    = (int*)  (ws + 36160000);     // 400 KB (NN+1)
    int2*  meta   = (int2*) (ws + 37400000);     //  8.0 MB
    int*   deg    = (int*)  (ws + 45400000);     // 400 KB
    int*   tmp    = (int*)  (ws + 46600000);     // 400 KB
    ushort* rank  = (ushort*)(ws + 47000000);    //  2.0 MB (NE ushorts)
    int*   bsum   = (int*)  (ws + 49000000);     //  ~2 KB
    int*   bpref  = (int*)  (ws + 49010000);     //  ~2 KB

    prep_wtb_kernel<<<12, 256, 0, stream>>>(Wp, Wn, Wf, WTB);
    prep_tables_kernel<<<NL, 256, 0, stream>>>(rela_embed, W1, Trel, Tq);

    // --- counting sort by dst (rank captured in hist; scatter atomic-free) ---
    hipMemsetAsync(deg, 0, NN * sizeof(int), stream);
    hist_kernel<<<(NE + 255) / 256, 256, 0, stream>>>(dst_idx, deg, rank);
    scan1_kernel<<<NBLK1, 256, 0, stream>>>(deg, tmp, bsum);
    scan2_kernel<<<1, 512, 0, stream>>>(bsum, bpref);
    scan3_kernel<<<NBLK1, 256, 0, stream>>>(deg, tmp, bpref, off);
    sort_scatter_kernel<<<(NE + 255) / 256, 256, 0, stream>>>(
        dst_idx, src_idx, rel_idx, rel_time, batch_idx, query_rel,
        off, rank, Trel, Tq, W2, meta, score);

    // --- layers: L0 -> hid0/projA ; L1 hid0,projA -> hid1/projB ;
    //             L2 hid1,projB -> hid0 ---
    int grid = (NN + 63) / 64;
    int sgrid = (NE + 255) / 256;
    {
        reduce_transform_kernel<true, true><<<grid, 256, 0, stream>>>(
            hid1, rela_embed, time_embed, score, meta, off,
            WTB, W1 + (size_t)1 * AD * 192, hid0, projA);
    }
    {
        const float* rela = rela_embed + (size_t)1 * NRL * HD;
        score_kernel<<<sgrid, 256, 0, stream>>>(
            projA, Trel + (size_t)1 * NRL * 8, Tq + (size_t)1 * NRL * 8,
            W2 + 1 * AD, meta, score);
        reduce_transform_kernel<false, true><<<grid, 256, 0, stream>>>(
            hid0, rela, time_embed, score, meta, off,
            WTB, W1 + (size_t)2 * AD * 192, hid1, projB);
    }
    {
        const float* rela = rela_embed + (size_t)2 * NRL * HD;
        score_kernel<<<sgrid, 256, 0, stream>>>(
            projB, Trel + (size_t)2 * NRL * 8, Tq + (size_t)2 * NRL * 8,
            W2 + 2 * AD, meta, score);
        reduce_transform_kernel<false, false><<<grid, 256, 0, stream>>>(
            hid1, rela, time_embed, score, meta, off,
            WTB, nullptr, hid0, nullptr);
    }

    out_kernel<<<(NOUT + 255) / 256, 256, 0, stream>>>(hid0, Wc, bc, out);
}

// Round 6
// 394.619 us; speedup vs baseline: 1.1036x; 1.0080x over previous
//
#include <hip/hip_runtime.h>

#define NB   32
#define NN   100000
#define NE   1000000
#define HD   64
#define AD   5
#define NL   3
#define NRL  231      // N_REL + 1
#define NTM  365
#define NOUT 228096   // 32 * 7128
#define NBLK1 391     // ceil(NN/256)
#define BLKN 32       // nodes per reduce block (NN = 3125 * 32 exactly)
#define NBLK2 3125    // NN / BLKN

// meta packing: w0 = src | (rel<<17) | (cls<<25) ; w1 = ta | (q<<9)

// bf16 helpers (hidden stored as bf16 to halve gather traffic)
__device__ __forceinline__ float bflo(unsigned u) { return __uint_as_float(u << 16); }
__device__ __forceinline__ float bfhi(unsigned u) { return __uint_as_float(u & 0xffff0000u); }
__device__ __forceinline__ unsigned packbf2(float x, float y) {
    unsigned ux = __float_as_uint(x), uy = __float_as_uint(y);
    ux = (ux + 0x7fffu + ((ux >> 16) & 1u)) >> 16;
    uy = (uy + 0x7fffu + ((uy >> 16) & 1u)) >> 16;
    return ux | (uy << 16);
}

using vbf8  = __attribute__((ext_vector_type(8))) short;   // 8 bf16 (4 VGPRs) MFMA A/B frag
using f32x4 = __attribute__((ext_vector_type(4))) float;   // MFMA C/D frag

// ---------------------------------------------------------------------------
// WTB: W in bf16 split (hi/lo) laid out as MFMA B-fragments.
// flat idx = ((((c*2 + hl)*2 + ks)*4 + nt)*64 + lane)*8 ushorts
// value(lane, j) = W_c[h = nt*16 + (lane&15)][k = ks*32 + (lane>>4)*8 + j]
// c: 0=Wf(pos) 1=Wn(zero) 2=Wp(neg); hl: 0=hi 1=residual
__global__ __launch_bounds__(256) void prep_wtb_kernel(
    const float* __restrict__ Wp, const float* __restrict__ Wn,
    const float* __restrict__ Wf, ushort* __restrict__ WTB)
{
    int i = blockIdx.x * 256 + threadIdx.x;
    if (i >= 3072) return;
    int lane = i & 63;
    int nt = (i >> 6) & 3;
    int ks = (i >> 8) & 1;
    int hl = (i >> 9) & 1;
    int c  = i >> 10;
    const float* W = (c == 0) ? Wf : (c == 1 ? Wn : Wp);
    int h  = nt * 16 + (lane & 15);
    int k0 = ks * 32 + (lane >> 4) * 8;
    unsigned up[4];
    #pragma unroll
    for (int j = 0; j < 4; ++j) {
        float x = W[h * 64 + k0 + 2 * j];
        float y = W[h * 64 + k0 + 2 * j + 1];
        unsigned pb = packbf2(x, y);
        if (hl) {
            float rx = x - bflo(pb);
            float ry = y - bfhi(pb);
            pb = packbf2(rx, ry);
        }
        up[j] = pb;
    }
    *(uint4*)(WTB + (size_t)i * 8) = make_uint4(up[0], up[1], up[2], up[3]);
}

// ---------------------------------------------------------------------------
__global__ __launch_bounds__(256) void prep_tables_kernel(
    const float* __restrict__ rela_embed,   // [3][231][64]
    const float* __restrict__ W1,           // [3][5][192]
    float* __restrict__ Trel,               // [3][231][8]
    float* __restrict__ Tq)                 // [3][231][8]
{
    int l = blockIdx.x;
    int r = threadIdx.x;
    if (r >= NRL) return;
    const float4* rrow = (const float4*)(rela_embed + ((size_t)l * NRL + r) * HD);
    const float* W1l = W1 + (size_t)l * AD * 192;
    float tr[AD] = {0,0,0,0,0}, tq[AD] = {0,0,0,0,0};
    #pragma unroll
    for (int k4 = 0; k4 < 16; ++k4) {
        float4 x = rrow[k4];
        #pragma unroll
        for (int a = 0; a < AD; ++a) {
            const float* wr = W1l + a * 192 + 64 + k4 * 4;
            const float* wq = W1l + a * 192 + 128 + k4 * 4;
            tr[a] = fmaf(x.x, wr[0], tr[a]); tr[a] = fmaf(x.y, wr[1], tr[a]);
            tr[a] = fmaf(x.z, wr[2], tr[a]); tr[a] = fmaf(x.w, wr[3], tr[a]);
            tq[a] = fmaf(x.x, wq[0], tq[a]); tq[a] = fmaf(x.y, wq[1], tq[a]);
            tq[a] = fmaf(x.z, wq[2], tq[a]); tq[a] = fmaf(x.w, wq[3], tq[a]);
        }
    }
    float* tro = Trel + ((size_t)l * NRL + r) * 8;
    float* tqo = Tq   + ((size_t)l * NRL + r) * 8;
    #pragma unroll
    for (int a = 0; a < AD; ++a) { tro[a] = tr[a]; tqo[a] = tq[a]; }
    tro[5] = tro[6] = tro[7] = 0.f;
    tqo[5] = tqo[6] = tqo[7] = 0.f;
}

// ---------------------------------------------------------------------------
// Counting sort by dst (dst-only: long segments keep MLP alive — R8 lesson).
// hist also captures each edge's rank within its dst bucket (the atomicAdd
// return we used to discard). The rank store is coalesced fire-and-forget,
// so hist doesn't stall; the scatter then needs NO atomic at all.
__global__ __launch_bounds__(256) void hist_kernel(
    const int* __restrict__ dst_idx, int* __restrict__ deg,
    ushort* __restrict__ rank)
{
    int e = blockIdx.x * 256 + threadIdx.x;
    if (e < NE) rank[e] = (ushort)atomicAdd(&deg[dst_idx[e]], 1);
}

__global__ __launch_bounds__(256) void scan1_kernel(
    const int* __restrict__ deg, int* __restrict__ tmp, int* __restrict__ bsum)
{
    __shared__ int s[256];
    int tid = threadIdx.x;
    int i = blockIdx.x * 256 + tid;
    int v = (i < NN) ? deg[i] : 0;
    s[tid] = v;
    __syncthreads();
    #pragma unroll
    for (int st = 1; st < 256; st <<= 1) {
        int t = (tid >= st) ? s[tid - st] : 0;
        __syncthreads();
        s[tid] += t;
        __syncthreads();
    }
    if (i < NN) tmp[i] = s[tid];
    if (tid == 255) bsum[blockIdx.x] = s[255];
}

__global__ __launch_bounds__(512) void scan2_kernel(
    const int* __restrict__ bsum, int* __restrict__ bpref)
{
    __shared__ int s[512];
    int tid = threadIdx.x;
    int v = (tid < NBLK1) ? bsum[tid] : 0;
    s[tid] = v;
    __syncthreads();
    #pragma unroll
    for (int st = 1; st < 512; st <<= 1) {
        int t = (tid >= st) ? s[tid - st] : 0;
        __syncthreads();
        s[tid] += t;
        __syncthreads();
    }
    if (tid < NBLK1) bpref[tid] = s[tid] - v;  // exclusive
}

__global__ __launch_bounds__(256) void scan3_kernel(
    const int* __restrict__ deg, const int* __restrict__ tmp,
    const int* __restrict__ bpref, int* __restrict__ off)
{
    int i = blockIdx.x * 256 + threadIdx.x;
    if (i >= NN) return;
    int incl = tmp[i] + bpref[i >> 8];
    off[i + 1] = incl;
    if (i == 0) off[0] = 0;
}

// scatter into dst-sorted order, ATOMIC-FREE: pos = off[d] + rank[e].
// off[d] is a plain cacheable read (400 KB, L1/L2-hot) — no per-address
// serialization, no RMW round trip (R3 lesson: the atomic return was the
// latency chain; the random stores themselves are fire-and-forget, so the
// layer-0 score scatter rides along for free).
__global__ __launch_bounds__(256) void sort_scatter_kernel(
    const int* __restrict__ dst_idx, const int* __restrict__ src_idx,
    const int* __restrict__ rel_idx, const int* __restrict__ rel_time,
    const int* __restrict__ batch_idx, const int* __restrict__ query_rel,
    const int* __restrict__ off, const ushort* __restrict__ rank,
    const float* __restrict__ Trel0, const float* __restrict__ Tq0,
    const float* __restrict__ W2,
    int2* __restrict__ meta, float* __restrict__ score0)
{
    int e = blockIdx.x * 256 + threadIdx.x;
    if (e >= NE) return;
    int d = dst_idx[e];
    int rt = rel_time[e];
    int cls = (rt > 0) ? 0 : ((rt == 0) ? 1 : 2);
    int ta = (rt < 0) ? -rt : rt;
    int rel = rel_idx[e];
    int q = query_rel[batch_idx[e]];
    int pos = off[d] + (int)rank[e];
    int2 m;
    m.x = src_idx[e] | (rel << 17) | (cls << 25);
    m.y = ta | (q << 9);
    meta[pos] = m;

    float4 t0 = *(const float4*)(Trel0 + rel * 8);
    float  t4 = Trel0[rel * 8 + 4];
    float4 u0 = *(const float4*)(Tq0 + q * 8);
    float  u4 = Tq0[q * 8 + 4];
    float z = 0.f;
    z = fmaf(fmaxf(t0.x + u0.x, 0.f), W2[0], z);
    z = fmaf(fmaxf(t0.y + u0.y, 0.f), W2[1], z);
    z = fmaf(fmaxf(t0.z + u0.z, 0.f), W2[2], z);
    z = fmaf(fmaxf(t0.w + u0.w, 0.f), W2[3], z);
    z = fmaf(fmaxf(t4   + u4,   0.f), W2[4], z);
    score0[pos] = 1.f / (1.f + __expf(-z));
}

// ---------------------------------------------------------------------------
// Standalone score for L1/L2 (64 edges/wave — R6 lesson).
__global__ __launch_bounds__(256) void score_kernel(
    const float* __restrict__ proj,     // [NN][8]
    const float* __restrict__ Trel,
    const float* __restrict__ Tq,
    const float* __restrict__ W2,
    const int2* __restrict__ meta,
    float* __restrict__ score)
{
    int j = blockIdx.x * 256 + threadIdx.x;
    if (j >= NE) return;
    int2 mt = meta[j];
    int rel = (mt.x >> 17) & 0xFF;
    int q   = (mt.y >> 9) & 0xFF;
    int src = mt.x & 0x1FFFF;

    float4 t0 = *(const float4*)(Trel + rel * 8);
    float  t4 = Trel[rel * 8 + 4];
    float4 u0 = *(const float4*)(Tq + q * 8);
    float  u4 = Tq[q * 8 + 4];
    float4 p0 = *(const float4*)(proj + (size_t)src * 8);
    float  p4 = proj[(size_t)src * 8 + 4];
    float z = 0.f;
    z = fmaf(fmaxf(p0.x + t0.x + u0.x, 0.f), W2[0], z);
    z = fmaf(fmaxf(p0.y + t0.y + u0.y, 0.f), W2[1], z);
    z = fmaf(fmaxf(p0.z + t0.z + u0.z, 0.f), W2[2], z);
    z = fmaf(fmaxf(p0.w + t0.w + u0.w, 0.f), W2[3], z);
    z = fmaf(fmaxf(p4   + t4   + u4,   0.f), W2[4], z);
    score[j] = 1.f / (1.f + __expf(-z));
}

// ---------------------------------------------------------------------------
// One edge, 8-lane group (lane covers h = hc*8..hc*8+7).
// A[6] = [cls0 h0..3, cls0 h4..7, cls1 lo, cls1 hi, cls2 lo, cls2 hi]
template <bool HZ>
__device__ __forceinline__ void edge1(
    int2 m, float sc, int hc8,
    const ushort* __restrict__ hidden_in,
    const float* __restrict__ rela, const float* __restrict__ temb,
    float4* __restrict__ A)
{
    int src = m.x & 0x1FFFF, rel = (m.x >> 17) & 0xFF;
    int cl  = (m.x >> 25) & 3, ta = m.y & 511;
    const float* rp = rela + rel * HD + hc8;
    const float* tp = temb + ta * HD + hc8;
    float4 rv0 = *(const float4*)rp;
    float4 rv1 = *(const float4*)(rp + 4);
    float4 tv0 = *(const float4*)tp;
    float4 tv1 = *(const float4*)(tp + 4);
    float4 v0, v1;
    v0.x = rv0.x + tv0.x; v0.y = rv0.y + tv0.y;
    v0.z = rv0.z + tv0.z; v0.w = rv0.w + tv0.w;
    v1.x = rv1.x + tv1.x; v1.y = rv1.y + tv1.y;
    v1.z = rv1.z + tv1.z; v1.w = rv1.w + tv1.w;
    if (!HZ) {
        uint4 hv = *(const uint4*)(hidden_in + (size_t)src * HD + hc8);
        v0.x += bflo(hv.x); v0.y += bfhi(hv.x);
        v0.z += bflo(hv.y); v0.w += bfhi(hv.y);
        v1.x += bflo(hv.z); v1.y += bfhi(hv.z);
        v1.z += bflo(hv.w); v1.w += bfhi(hv.w);
    }
    float sA = (cl == 0) ? sc : 0.f;
    float sB = (cl == 1) ? sc : 0.f;
    float sC = (cl == 2) ? sc : 0.f;
    A[0].x = fmaf(sA, v0.x, A[0].x); A[0].y = fmaf(sA, v0.y, A[0].y);
    A[0].z = fmaf(sA, v0.z, A[0].z); A[0].w = fmaf(sA, v0.w, A[0].w);
    A[1].x = fmaf(sA, v1.x, A[1].x); A[1].y = fmaf(sA, v1.y, A[1].y);
    A[1].z = fmaf(sA, v1.z, A[1].z); A[1].w = fmaf(sA, v1.w, A[1].w);
    A[2].x = fmaf(sB, v0.x, A[2].x); A[2].y = fmaf(sB, v0.y, A[2].y);
    A[2].z = fmaf(sB, v0.z, A[2].z); A[2].w = fmaf(sB, v0.w, A[2].w);
    A[3].x = fmaf(sB, v1.x, A[3].x); A[3].y = fmaf(sB, v1.y, A[3].y);
    A[3].z = fmaf(sB, v1.z, A[3].z); A[3].w = fmaf(sB, v1.w, A[3].w);
    A[4].x = fmaf(sC, v0.x, A[4].x); A[4].y = fmaf(sC, v0.y, A[4].y);
    A[4].z = fmaf(sC, v0.z, A[4].z); A[4].w = fmaf(sC, v0.w, A[4].w);
    A[5].x = fmaf(sC, v1.x, A[5].x); A[5].y = fmaf(sC, v1.y, A[5].y);
    A[5].z = fmaf(sC, v1.z, A[5].z); A[5].w = fmaf(sC, v1.w, A[5].w);
}

// ---------------------------------------------------------------------------
// Fused segmented-reduce + MFMA transform + next-layer proj epilogue.
// R5 restructure: 32-node tile, ONE node per 8-lane group (no serial rr
// loop) — halves the accumulator to a[6] (24 VGPRs) and doubles the number
// of independent gather streams for the latency-bound edge phase.
// Transform: wave w owns row-tile rt=w&1 (16 nodes) x col-pair ct=w>>1
// (nt = 2ct, 2ct+1): accd[2], 36 MFMAs/wave. Same split-bf16 algebra as the
// verified 64-node version. LDS: 32 rows x 68 uints = 8704 B.
// Epilogue: thread = (node nd=tid>>3, h-octet ho=tid&7): coalesced uint4
// hidden store; proj partials reduced across the 8 octet-threads via LDS.
#define SPITCH 68
template <bool HZ, bool PROJ>
__global__ __launch_bounds__(256, 4) void reduce_transform_kernel(
    const ushort* __restrict__ hidden_in,   // bf16 [NN][64]
    const float* __restrict__ rela,         // layer slice [231][64] fp32
    const float* __restrict__ temb,         // [365][64] fp32
    const float* __restrict__ score,        // [E] sorted
    const int2* __restrict__ meta,          // [E] sorted
    const int*  __restrict__ off,           // [NN+1]
    const ushort* __restrict__ WTB,         // bf16 split W frags [3][2][2][4][64][8]
    const float* __restrict__ W1next,       // next layer slice [5][192] (if PROJ)
    ushort* __restrict__ hidden_out,        // bf16 [NN][64]
    float* __restrict__ proj_out)           // [NN][8] (if PROJ)
{
    __shared__ float lds_t[BLKN * SPITCH];   // 8704 B
    int tid  = threadIdx.x;
    int lane = tid & 63;
    int w    = __builtin_amdgcn_readfirstlane(tid >> 6);  // 0..3
    int gid  = tid >> 3;                                   // 0..31 (node group)
    int hc   = tid & 7;                                    // 0..7
    int hc8  = hc * 8;
    int node0 = blockIdx.x * BLKN;
    int node  = node0 + gid;                               // NN = 3125*32: always valid

    float4 a[6];
    #pragma unroll
    for (int c = 0; c < 6; ++c)
        a[c] = make_float4(0.f, 0.f, 0.f, 0.f);

    {
        int o0 = off[node];
        int o1 = off[node + 1];
        int j = o0;
        for (; j + 2 <= o1; j += 2) {
            int2 m0 = meta[j], m1 = meta[j + 1];
            float s0 = score[j], s1 = score[j + 1];
            edge1<HZ>(m0, s0, hc8, hidden_in, rela, temb, a);
            edge1<HZ>(m1, s1, hc8, hidden_in, rela, temb, a);
        }
        if (j < o1)
            edge1<HZ>(meta[j], score[j], hc8, hidden_in, rela, temb, a);
    }

    // --- transform via split-bf16 MFMA, one class slab at a time ---
    unsigned* lds_u = (unsigned*)lds_t;
    int rl = lane & 15;
    int t  = lane >> 4;
    int rt = w & 1;    // row-tile (nodes rt*16..rt*16+15)
    int ct = w >> 1;   // col-pair (nt = 2ct, 2ct+1)
    f32x4 accd[2];
    accd[0] = (f32x4){0.f, 0.f, 0.f, 0.f};
    accd[1] = (f32x4){0.f, 0.f, 0.f, 0.f};

    #pragma unroll
    for (int c = 0; c < 3; ++c) {
        __syncthreads();   // protect previous slab's reads
        {
            float4 v0 = a[2 * c];
            float4 v1 = a[2 * c + 1];
            unsigned p0 = packbf2(v0.x, v0.y);
            unsigned p1 = packbf2(v0.z, v0.w);
            unsigned p2 = packbf2(v1.x, v1.y);
            unsigned p3 = packbf2(v1.z, v1.w);
            unsigned q0 = packbf2(v0.x - bflo(p0), v0.y - bfhi(p0));
            unsigned q1 = packbf2(v0.z - bflo(p1), v0.w - bfhi(p1));
            unsigned q2 = packbf2(v1.x - bflo(p2), v1.y - bfhi(p2));
            unsigned q3 = packbf2(v1.z - bflo(p3), v1.w - bfhi(p3));
            *(uint4*)(lds_u + gid * SPITCH + hc * 4)      = make_uint4(p0, p1, p2, p3);
            *(uint4*)(lds_u + gid * SPITCH + 32 + hc * 4) = make_uint4(q0, q1, q2, q3);
        }
        __syncthreads();
        #pragma unroll
        for (int ks = 0; ks < 2; ++ks) {
            const unsigned* rowp = lds_u + (rt * 16 + rl) * SPITCH + ks * 16 + t * 4;
            vbf8 ah = *(const vbf8*)rowp;
            vbf8 al = *(const vbf8*)(rowp + 32);
            #pragma unroll
            for (int b = 0; b < 2; ++b) {
                int nt = ct * 2 + b;
                const ushort* bp = WTB +
                    (size_t)((((c * 2) * 2 + ks) * 4 + nt) * 64 + lane) * 8;
                vbf8 bh = *(const vbf8*)bp;
                vbf8 bl = *(const vbf8*)(bp + 4096);   // hl=1 plane
                accd[b] = __builtin_amdgcn_mfma_f32_16x16x32_bf16(ah, bh, accd[b], 0, 0, 0);
                accd[b] = __builtin_amdgcn_mfma_f32_16x16x32_bf16(al, bh, accd[b], 0, 0, 0);
                accd[b] = __builtin_amdgcn_mfma_f32_16x16x32_bf16(ah, bl, accd[b], 0, 0, 0);
            }
        }
    }

    // D frag (col=lane&15, row=(lane>>4)*4+i) -> LDS [node][h] fp32
    __syncthreads();
    #pragma unroll
    for (int b = 0; b < 2; ++b)
        #pragma unroll
        for (int i = 0; i < 4; ++i)
            lds_t[(rt * 16 + t * 4 + i) * SPITCH + (ct * 2 + b) * 16 + rl] = accd[b][i];
    __syncthreads();

    // readback: thread owns node nd = gid, h-octet ho = hc
    float acc8[8];
    {
        const float4* rp = (const float4*)(lds_t + gid * SPITCH + hc8);
        float4 x = rp[0], y = rp[1];
        acc8[0] = x.x; acc8[1] = x.y; acc8[2] = x.z; acc8[3] = x.w;
        acc8[4] = y.x; acc8[5] = y.y; acc8[6] = y.z; acc8[7] = y.w;
    }

    {
        ushort* outp = hidden_out + (size_t)node * 64 + hc8;
        unsigned u0 = packbf2(fmaxf(acc8[0], 0.f), fmaxf(acc8[1], 0.f));
        unsigned u1 = packbf2(fmaxf(acc8[2], 0.f), fmaxf(acc8[3], 0.f));
        unsigned u2 = packbf2(fmaxf(acc8[4], 0.f), fmaxf(acc8[5], 0.f));
        unsigned u3 = packbf2(fmaxf(acc8[6], 0.f), fmaxf(acc8[7], 0.f));
        *(uint4*)outp = make_uint4(u0, u1, u2, u3);
    }

    // --- epilogue: proj for NEXT layer from fp32 acc (exact) ---
    if (PROJ) {
        float pa[AD];
        #pragma unroll
        for (int aa = 0; aa < AD; ++aa) pa[aa] = 0.f;
        #pragma unroll
        for (int i = 0; i < 8; ++i) {
            float hv = fmaxf(acc8[i], 0.f);
            #pragma unroll
            for (int aa = 0; aa < AD; ++aa)
                pa[aa] = fmaf(hv, W1next[aa * 192 + hc8 + i], pa[aa]);
        }
        __syncthreads();
        float* lds2 = lds_t;   // reuse as [256][AD]
        #pragma unroll
        for (int aa = 0; aa < AD; ++aa)
            lds2[tid * AD + aa] = pa[aa];
        __syncthreads();
        int nd = tid >> 3, aa = tid & 7;
        float v = 0.f;
        if (aa < AD) {
            #pragma unroll
            for (int ho = 0; ho < 8; ++ho)
                v += lds2[(nd * 8 + ho) * AD + aa];
        }
        proj_out[(size_t)(node0 + nd) * 8 + aa] = v;
    }
}

// ---------------------------------------------------------------------------
__global__ __launch_bounds__(256) void out_kernel(
    const ushort* __restrict__ hidden,   // bf16 [NN][64]
    const float* __restrict__ Wc,
    const float* __restrict__ bc,
    float* __restrict__ out)
{
    int i = blockIdx.x * 256 + threadIdx.x;
    if (i >= NOUT) return;
    float r = 0.f;
    if (i < NN) {
        const uint4* h4 = (const uint4*)(hidden + (size_t)i * 64);
        float acc = 0.f;
        #pragma unroll
        for (int q = 0; q < 8; ++q) {
            uint4 hv = h4[q];
            const float* wq = Wc + q * 8;
            acc = fmaf(bflo(hv.x), wq[0], acc);
            acc = fmaf(bfhi(hv.x), wq[1], acc);
            acc = fmaf(bflo(hv.y), wq[2], acc);
            acc = fmaf(bfhi(hv.y), wq[3], acc);
            acc = fmaf(bflo(hv.z), wq[4], acc);
            acc = fmaf(bfhi(hv.z), wq[5], acc);
            acc = fmaf(bflo(hv.w), wq[6], acc);
            acc = fmaf(bfhi(hv.w), wq[7], acc);
        }
        r = acc + bc[0];
    }
    out[i] = r;
}

// ---------------------------------------------------------------------------
extern "C" void kernel_launch(void* const* d_in, const int* in_sizes, int n_in,
                              void* d_out, int out_size, void* d_ws, size_t ws_size,
                              hipStream_t stream)
{
    const int*   batch_idx  = (const int*)d_in[0];
    const int*   src_idx    = (const int*)d_in[1];
    const int*   dst_idx    = (const int*)d_in[2];
    const int*   rel_idx    = (const int*)d_in[3];
    const int*   rel_time   = (const int*)d_in[4];
    const int*   query_rel  = (const int*)d_in[5];
    const float* rela_embed = (const float*)d_in[8];   // [3][231][64]
    const float* time_embed = (const float*)d_in[9];   // [365][64]
    const float* Wp         = (const float*)d_in[10];
    const float* Wn         = (const float*)d_in[11];
    const float* Wf         = (const float*)d_in[12];
    const float* W1         = (const float*)d_in[13];  // [3][5][192]
    const float* W2         = (const float*)d_in[14];  // [3][1][5]
    const float* Wc         = (const float*)d_in[15];  // [64]
    const float* bc         = (const float*)d_in[16];  // [1]
    float* out = (float*)d_out;

    char* ws = (char*)d_ws;
    ushort* hid0  = (ushort*)(ws + 0);           // 12.8 MB bf16
    ushort* hid1  = (ushort*)(ws + 12800000);    // 12.8 MB bf16
    float* projA  = (float*)(ws + 25600000);     //  3.2 MB
    float* projB  = (float*)(ws + 28800000);     //  3.2 MB
    float* score  = (float*)(ws + 32000000);     //  4.0 MB
    ushort* WTB   = (ushort*)(ws + 36000000);    //  48 KB bf16 split W frags
    float* Trel   = (float*)(ws + 36100000);     //  ~22 KB
    float* Tq     = (float*)(ws + 36130000);     //  ~22 KB
    int*   off    = (int*)  (ws + 36160000);     // 400 KB (NN+1)
    int2*  meta   = (int2*) (ws + 37400000);     //  8.0 MB
    int*   deg    = (int*)  (ws + 45400000);     // 400 KB
    int*   tmp    = (int*)  (ws + 46600000);     // 400 KB
    ushort* rank  = (ushort*)(ws + 47000000);    //  2.0 MB (NE ushorts)
    int*   bsum   = (int*)  (ws + 49000000);     //  ~2 KB
    int*   bpref  = (int*)  (ws + 49010000);     //  ~2 KB

    prep_wtb_kernel<<<12, 256, 0, stream>>>(Wp, Wn, Wf, WTB);
    prep_tables_kernel<<<NL, 256, 0, stream>>>(rela_embed, W1, Trel, Tq);

    // --- counting sort by dst (rank captured in hist; scatter atomic-free) ---
    hipMemsetAsync(deg, 0, NN * sizeof(int), stream);
    hist_kernel<<<(NE + 255) / 256, 256, 0, stream>>>(dst_idx, deg, rank);
    scan1_kernel<<<NBLK1, 256, 0, stream>>>(deg, tmp, bsum);
    scan2_kernel<<<1, 512, 0, stream>>>(bsum, bpref);
    scan3_kernel<<<NBLK1, 256, 0, stream>>>(deg, tmp, bpref, off);
    sort_scatter_kernel<<<(NE + 255) / 256, 256, 0, stream>>>(
        dst_idx, src_idx, rel_idx, rel_time, batch_idx, query_rel,
        off, rank, Trel, Tq, W2, meta, score);

    // --- layers: L0 -> hid0/projA ; L1 hid0,projA -> hid1/projB ;
    //             L2 hid1,projB -> hid0 ---
    int grid = NBLK2;
    int sgrid = (NE + 255) / 256;
    {
        reduce_transform_kernel<true, true><<<grid, 256, 0, stream>>>(
            hid1, rela_embed, time_embed, score, meta, off,
            WTB, W1 + (size_t)1 * AD * 192, hid0, projA);
    }
    {
        const float* rela = rela_embed + (size_t)1 * NRL * HD;
        score_kernel<<<sgrid, 256, 0, stream>>>(
            projA, Trel + (size_t)1 * NRL * 8, Tq + (size_t)1 * NRL * 8,
            W2 + 1 * AD, meta, score);
        reduce_transform_kernel<false, true><<<grid, 256, 0, stream>>>(
            hid0, rela, time_embed, score, meta, off,
            WTB, W1 + (size_t)2 * AD * 192, hid1, projB);
    }
    {
        const float* rela = rela_embed + (size_t)2 * NRL * HD;
        score_kernel<<<sgrid, 256, 0, stream>>>(
            projB, Trel + (size_t)2 * NRL * 8, Tq + (size_t)2 * NRL * 8,
            W2 + 2 * AD, meta, score);
        reduce_transform_kernel<false, false><<<grid, 256, 0, stream>>>(
            hid1, rela, time_embed, score, meta, off,
            WTB, nullptr, hid0, nullptr);
    }

    out_kernel<<<(NOUT + 255) / 256, 256, 0, stream>>>(hid0, Wc, bc, out);
}

// Round 8
// 379.968 us; speedup vs baseline: 1.1462x; 1.0386x over previous
//
#include <hip/hip_runtime.h>

#define NB   32
#define NN   100000
#define NE   1000000
#define HD   64
#define AD   5
#define NL   3
#define NRL  231      // N_REL + 1
#define NTM  365
#define NOUT 228096   // 32 * 7128
#define NBLK1 391     // ceil(NN/256)
#define BLKN 32       // nodes per reduce block (NN = 3125 * 32 exactly)
#define NBLK2 3125    // NN / BLKN

// meta packing: w0 = src | (rel<<17) | (cls<<25) ; w1 = ta | (q<<9)

// bf16 helpers (hidden stored as bf16 to halve gather traffic)
__device__ __forceinline__ float bflo(unsigned u) { return __uint_as_float(u << 16); }
__device__ __forceinline__ float bfhi(unsigned u) { return __uint_as_float(u & 0xffff0000u); }
__device__ __forceinline__ unsigned packbf2(float x, float y) {
    unsigned ux = __float_as_uint(x), uy = __float_as_uint(y);
    ux = (ux + 0x7fffu + ((ux >> 16) & 1u)) >> 16;
    uy = (uy + 0x7fffu + ((uy >> 16) & 1u)) >> 16;
    return ux | (uy << 16);
}

using vbf8  = __attribute__((ext_vector_type(8))) short;   // 8 bf16 (4 VGPRs) MFMA A/B frag
using f32x4 = __attribute__((ext_vector_type(4))) float;   // MFMA C/D frag

// ---------------------------------------------------------------------------
// WTB: W in bf16 split (hi/lo) laid out as MFMA B-fragments.
// flat idx = ((((c*2 + hl)*2 + ks)*4 + nt)*64 + lane)*8 ushorts
// value(lane, j) = W_c[h = nt*16 + (lane&15)][k = ks*32 + (lane>>4)*8 + j]
// c: 0=Wf(pos) 1=Wn(zero) 2=Wp(neg); hl: 0=hi 1=residual
__global__ __launch_bounds__(256) void prep_wtb_kernel(
    const float* __restrict__ Wp, const float* __restrict__ Wn,
    const float* __restrict__ Wf, ushort* __restrict__ WTB)
{
    int i = blockIdx.x * 256 + threadIdx.x;
    if (i >= 3072) return;
    int lane = i & 63;
    int nt = (i >> 6) & 3;
    int ks = (i >> 8) & 1;
    int hl = (i >> 9) & 1;
    int c  = i >> 10;
    const float* W = (c == 0) ? Wf : (c == 1 ? Wn : Wp);
    int h  = nt * 16 + (lane & 15);
    int k0 = ks * 32 + (lane >> 4) * 8;
    unsigned up[4];
    #pragma unroll
    for (int j = 0; j < 4; ++j) {
        float x = W[h * 64 + k0 + 2 * j];
        float y = W[h * 64 + k0 + 2 * j + 1];
        unsigned pb = packbf2(x, y);
        if (hl) {
            float rx = x - bflo(pb);
            float ry = y - bfhi(pb);
            pb = packbf2(rx, ry);
        }
        up[j] = pb;
    }
    *(uint4*)(WTB + (size_t)i * 8) = make_uint4(up[0], up[1], up[2], up[3]);
}

// ---------------------------------------------------------------------------
// bf16 copies of rela (all 3 layer slices) and temb for the edge-gather phase:
// halves per-edge table load instructions AND halves table cache footprint
// (152 KB fp32 -> 76 KB bf16; L1 is 32 KB -> much higher hit rate).
__global__ __launch_bounds__(256) void prep_tb_kernel(
    const float* __restrict__ rela_embed,  // [3][231][64]
    const float* __restrict__ time_embed,  // [365][64]
    ushort* __restrict__ relb,             // [3][231][64] bf16
    ushort* __restrict__ tembb)            // [365][64] bf16
{
    const int nrel_w = 3 * NRL * HD / 2;   // 22176 packed words
    const int ntmb_w = NTM * HD / 2;       // 11680
    int i = blockIdx.x * 256 + threadIdx.x;
    if (i < nrel_w) {
        ((unsigned*)relb)[i] = packbf2(rela_embed[2 * i], rela_embed[2 * i + 1]);
    } else if (i < nrel_w + ntmb_w) {
        int k = i - nrel_w;
        ((unsigned*)tembb)[k] = packbf2(time_embed[2 * k], time_embed[2 * k + 1]);
    }
}

// ---------------------------------------------------------------------------
__global__ __launch_bounds__(256) void prep_tables_kernel(
    const float* __restrict__ rela_embed,   // [3][231][64]
    const float* __restrict__ W1,           // [3][5][192]
    float* __restrict__ Trel,               // [3][231][8]
    float* __restrict__ Tq)                 // [3][231][8]
{
    int l = blockIdx.x;
    int r = threadIdx.x;
    if (r >= NRL) return;
    const float4* rrow = (const float4*)(rela_embed + ((size_t)l * NRL + r) * HD);
    const float* W1l = W1 + (size_t)l * AD * 192;
    float tr[AD] = {0,0,0,0,0}, tq[AD] = {0,0,0,0,0};
    #pragma unroll
    for (int k4 = 0; k4 < 16; ++k4) {
        float4 x = rrow[k4];
        #pragma unroll
        for (int a = 0; a < AD; ++a) {
            const float* wr = W1l + a * 192 + 64 + k4 * 4;
            const float* wq = W1l + a * 192 + 128 + k4 * 4;
            tr[a] = fmaf(x.x, wr[0], tr[a]); tr[a] = fmaf(x.y, wr[1], tr[a]);
            tr[a] = fmaf(x.z, wr[2], tr[a]); tr[a] = fmaf(x.w, wr[3], tr[a]);
            tq[a] = fmaf(x.x, wq[0], tq[a]); tq[a] = fmaf(x.y, wq[1], tq[a]);
            tq[a] = fmaf(x.z, wq[2], tq[a]); tq[a] = fmaf(x.w, wq[3], tq[a]);
        }
    }
    float* tro = Trel + ((size_t)l * NRL + r) * 8;
    float* tqo = Tq   + ((size_t)l * NRL + r) * 8;
    #pragma unroll
    for (int a = 0; a < AD; ++a) { tro[a] = tr[a]; tqo[a] = tq[a]; }
    tro[5] = tro[6] = tro[7] = 0.f;
    tqo[5] = tqo[6] = tqo[7] = 0.f;
}

// ---------------------------------------------------------------------------
// Counting sort by dst (dst-only: long segments keep MLP alive — R8 lesson).
// hist captures each edge's rank within its dst bucket (atomicAdd return);
// rank store is coalesced fire-and-forget, so hist doesn't stall; the
// scatter then needs NO atomic at all (R5 win).
__global__ __launch_bounds__(256) void hist_kernel(
    const int* __restrict__ dst_idx, int* __restrict__ deg,
    ushort* __restrict__ rank)
{
    int e = blockIdx.x * 256 + threadIdx.x;
    if (e < NE) rank[e] = (ushort)atomicAdd(&deg[dst_idx[e]], 1);
}

__global__ __launch_bounds__(256) void scan1_kernel(
    const int* __restrict__ deg, int* __restrict__ tmp, int* __restrict__ bsum)
{
    __shared__ int s[256];
    int tid = threadIdx.x;
    int i = blockIdx.x * 256 + tid;
    int v = (i < NN) ? deg[i] : 0;
    s[tid] = v;
    __syncthreads();
    #pragma unroll
    for (int st = 1; st < 256; st <<= 1) {
        int t = (tid >= st) ? s[tid - st] : 0;
        __syncthreads();
        s[tid] += t;
        __syncthreads();
    }
    if (i < NN) tmp[i] = s[tid];
    if (tid == 255) bsum[blockIdx.x] = s[255];
}

__global__ __launch_bounds__(512) void scan2_kernel(
    const int* __restrict__ bsum, int* __restrict__ bpref)
{
    __shared__ int s[512];
    int tid = threadIdx.x;
    int v = (tid < NBLK1) ? bsum[tid] : 0;
    s[tid] = v;
    __syncthreads();
    #pragma unroll
    for (int st = 1; st < 512; st <<= 1) {
        int t = (tid >= st) ? s[tid - st] : 0;
        __syncthreads();
        s[tid] += t;
        __syncthreads();
    }
    if (tid < NBLK1) bpref[tid] = s[tid] - v;  // exclusive
}

__global__ __launch_bounds__(256) void scan3_kernel(
    const int* __restrict__ deg, const int* __restrict__ tmp,
    const int* __restrict__ bpref, int* __restrict__ off)
{
    int i = blockIdx.x * 256 + threadIdx.x;
    if (i >= NN) return;
    int incl = tmp[i] + bpref[i >> 8];
    off[i + 1] = incl;
    if (i == 0) off[0] = 0;
}

// scatter into dst-sorted order, ATOMIC-FREE: pos = off[d] + rank[e].
__global__ __launch_bounds__(256) void sort_scatter_kernel(
    const int* __restrict__ dst_idx, const int* __restrict__ src_idx,
    const int* __restrict__ rel_idx, const int* __restrict__ rel_time,
    const int* __restrict__ batch_idx, const int* __restrict__ query_rel,
    const int* __restrict__ off, const ushort* __restrict__ rank,
    const float* __restrict__ Trel0, const float* __restrict__ Tq0,
    const float* __restrict__ W2,
    int2* __restrict__ meta, float* __restrict__ score0)
{
    int e = blockIdx.x * 256 + threadIdx.x;
    if (e >= NE) return;
    int d = dst_idx[e];
    int rt = rel_time[e];
    int cls = (rt > 0) ? 0 : ((rt == 0) ? 1 : 2);
    int ta = (rt < 0) ? -rt : rt;
    int rel = rel_idx[e];
    int q = query_rel[batch_idx[e]];
    int pos = off[d] + (int)rank[e];
    int2 m;
    m.x = src_idx[e] | (rel << 17) | (cls << 25);
    m.y = ta | (q << 9);
    meta[pos] = m;

    float4 t0 = *(const float4*)(Trel0 + rel * 8);
    float  t4 = Trel0[rel * 8 + 4];
    float4 u0 = *(const float4*)(Tq0 + q * 8);
    float  u4 = Tq0[q * 8 + 4];
    float z = 0.f;
    z = fmaf(fmaxf(t0.x + u0.x, 0.f), W2[0], z);
    z = fmaf(fmaxf(t0.y + u0.y, 0.f), W2[1], z);
    z = fmaf(fmaxf(t0.z + u0.z, 0.f), W2[2], z);
    z = fmaf(fmaxf(t0.w + u0.w, 0.f), W2[3], z);
    z = fmaf(fmaxf(t4   + u4,   0.f), W2[4], z);
    score0[pos] = 1.f / (1.f + __expf(-z));
}

// ---------------------------------------------------------------------------
// Standalone score for L1/L2 (64 edges/wave — R6 lesson).
__global__ __launch_bounds__(256) void score_kernel(
    const float* __restrict__ proj,     // [NN][8]
    const float* __restrict__ Trel,
    const float* __restrict__ Tq,
    const float* __restrict__ W2,
    const int2* __restrict__ meta,
    float* __restrict__ score)
{
    int j = blockIdx.x * 256 + threadIdx.x;
    if (j >= NE) return;
    int2 mt = meta[j];
    int rel = (mt.x >> 17) & 0xFF;
    int q   = (mt.y >> 9) & 0xFF;
    int src = mt.x & 0x1FFFF;

    float4 t0 = *(const float4*)(Trel + rel * 8);
    float  t4 = Trel[rel * 8 + 4];
    float4 u0 = *(const float4*)(Tq + q * 8);
    float  u4 = Tq[q * 8 + 4];
    float4 p0 = *(const float4*)(proj + (size_t)src * 8);
    float  p4 = proj[(size_t)src * 8 + 4];
    float z = 0.f;
    z = fmaf(fmaxf(p0.x + t0.x + u0.x, 0.f), W2[0], z);
    z = fmaf(fmaxf(p0.y + t0.y + u0.y, 0.f), W2[1], z);
    z = fmaf(fmaxf(p0.z + t0.z + u0.z, 0.f), W2[2], z);
    z = fmaf(fmaxf(p0.w + t0.w + u0.w, 0.f), W2[3], z);
    z = fmaf(fmaxf(p4   + t4   + u4,   0.f), W2[4], z);
    score[j] = 1.f / (1.f + __expf(-z));
}

// ---------------------------------------------------------------------------
// Accumulate one edge from preloaded bf16 rows (rv=rela, tv=temb, hv=hidden).
// A[6] = [cls0 h0..3, cls0 h4..7, cls1 lo, cls1 hi, cls2 lo, cls2 hi]
template <bool HZ>
__device__ __forceinline__ void edge_acc(
    int mx, float sc, uint4 rv, uint4 tv, uint4 hv, float4* __restrict__ A)
{
    int cl = (mx >> 25) & 3;
    float4 v0, v1;
    v0.x = bflo(rv.x) + bflo(tv.x); v0.y = bfhi(rv.x) + bfhi(tv.x);
    v0.z = bflo(rv.y) + bflo(tv.y); v0.w = bfhi(rv.y) + bfhi(tv.y);
    v1.x = bflo(rv.z) + bflo(tv.z); v1.y = bfhi(rv.z) + bfhi(tv.z);
    v1.z = bflo(rv.w) + bflo(tv.w); v1.w = bfhi(rv.w) + bfhi(tv.w);
    if (!HZ) {
        v0.x += bflo(hv.x); v0.y += bfhi(hv.x);
        v0.z += bflo(hv.y); v0.w += bfhi(hv.y);
        v1.x += bflo(hv.z); v1.y += bfhi(hv.z);
        v1.z += bflo(hv.w); v1.w += bfhi(hv.w);
    }
    float sA = (cl == 0) ? sc : 0.f;
    float sB = (cl == 1) ? sc : 0.f;
    float sC = (cl == 2) ? sc : 0.f;
    A[0].x = fmaf(sA, v0.x, A[0].x); A[0].y = fmaf(sA, v0.y, A[0].y);
    A[0].z = fmaf(sA, v0.z, A[0].z); A[0].w = fmaf(sA, v0.w, A[0].w);
    A[1].x = fmaf(sA, v1.x, A[1].x); A[1].y = fmaf(sA, v1.y, A[1].y);
    A[1].z = fmaf(sA, v1.z, A[1].z); A[1].w = fmaf(sA, v1.w, A[1].w);
    A[2].x = fmaf(sB, v0.x, A[2].x); A[2].y = fmaf(sB, v0.y, A[2].y);
    A[2].z = fmaf(sB, v0.z, A[2].z); A[2].w = fmaf(sB, v0.w, A[2].w);
    A[3].x = fmaf(sB, v1.x, A[3].x); A[3].y = fmaf(sB, v1.y, A[3].y);
    A[3].z = fmaf(sB, v1.z, A[3].z); A[3].w = fmaf(sB, v1.w, A[3].w);
    A[4].x = fmaf(sC, v0.x, A[4].x); A[4].y = fmaf(sC, v0.y, A[4].y);
    A[4].z = fmaf(sC, v0.z, A[4].z); A[4].w = fmaf(sC, v0.w, A[4].w);
    A[5].x = fmaf(sC, v1.x, A[5].x); A[5].y = fmaf(sC, v1.y, A[5].y);
    A[5].z = fmaf(sC, v1.z, A[5].z); A[5].w = fmaf(sC, v1.w, A[5].w);
}

__device__ __forceinline__ uint4 ldrow(const ushort* __restrict__ base, int row, int hc8)
{
    return *(const uint4*)(base + (size_t)row * HD + hc8);
}

// ---------------------------------------------------------------------------
// Fused segmented-reduce + MFMA transform + next-layer proj epilogue.
// R6: 32-node tile, one node per 8-lane group (a[6] = 24 VGPR acc).
// R7: bf16 rela/temb tables (5 loads/edge instead of 7) + 4-edge unroll
// (4 independent gather chains in flight; edge phase is latency-bound).
// Transform: wave w owns row-tile rt=w&1 x col-pair ct=w>>1 (36 MFMAs/wave),
// split-bf16 (hi+residual) algebra, fp32 accumulate — unchanged from the
// verified R5/R6 versions. LDS: 32 x 68 uints = 8704 B.
#define SPITCH 68
template <bool HZ, bool PROJ>
__global__ __launch_bounds__(256, 4) void reduce_transform_kernel(
    const ushort* __restrict__ hidden_in,   // bf16 [NN][64]
    const ushort* __restrict__ relb,        // layer slice [231][64] bf16
    const ushort* __restrict__ tembb,       // [365][64] bf16
    const float* __restrict__ score,        // [E] sorted
    const int2* __restrict__ meta,          // [E] sorted
    const int*  __restrict__ off,           // [NN+1]
    const ushort* __restrict__ WTB,         // bf16 split W frags [3][2][2][4][64][8]
    const float* __restrict__ W1next,       // next layer slice [5][192] (if PROJ)
    ushort* __restrict__ hidden_out,        // bf16 [NN][64]
    float* __restrict__ proj_out)           // [NN][8] (if PROJ)
{
    __shared__ float lds_t[BLKN * SPITCH];   // 8704 B
    int tid  = threadIdx.x;
    int lane = tid & 63;
    int w    = __builtin_amdgcn_readfirstlane(tid >> 6);  // 0..3
    int gid  = tid >> 3;                                   // 0..31 (node group)
    int hc   = tid & 7;                                    // 0..7
    int hc8  = hc * 8;
    int node0 = blockIdx.x * BLKN;
    int node  = node0 + gid;                               // NN = 3125*32: always valid

    float4 a[6];
    #pragma unroll
    for (int c = 0; c < 6; ++c)
        a[c] = make_float4(0.f, 0.f, 0.f, 0.f);

    {
        int o0 = off[node];
        int o1 = off[node + 1];
        int j = o0;
        const uint4 zz = make_uint4(0, 0, 0, 0);
        for (; j + 4 <= o1; j += 4) {
            // load phase: 4 independent chains
            int2 m0 = meta[j],     m1 = meta[j + 1];
            int2 m2 = meta[j + 2], m3 = meta[j + 3];
            float s0 = score[j],     s1 = score[j + 1];
            float s2 = score[j + 2], s3 = score[j + 3];
            uint4 r0 = ldrow(relb, (m0.x >> 17) & 0xFF, hc8);
            uint4 r1 = ldrow(relb, (m1.x >> 17) & 0xFF, hc8);
            uint4 r2 = ldrow(relb, (m2.x >> 17) & 0xFF, hc8);
            uint4 r3 = ldrow(relb, (m3.x >> 17) & 0xFF, hc8);
            uint4 t0 = ldrow(tembb, m0.y & 511, hc8);
            uint4 t1 = ldrow(tembb, m1.y & 511, hc8);
            uint4 t2 = ldrow(tembb, m2.y & 511, hc8);
            uint4 t3 = ldrow(tembb, m3.y & 511, hc8);
            uint4 h0 = zz, h1 = zz, h2 = zz, h3 = zz;
            if (!HZ) {
                h0 = ldrow(hidden_in, m0.x & 0x1FFFF, hc8);
                h1 = ldrow(hidden_in, m1.x & 0x1FFFF, hc8);
                h2 = ldrow(hidden_in, m2.x & 0x1FFFF, hc8);
                h3 = ldrow(hidden_in, m3.x & 0x1FFFF, hc8);
            }
            edge_acc<HZ>(m0.x, s0, r0, t0, h0, a);
            edge_acc<HZ>(m1.x, s1, r1, t1, h1, a);
            edge_acc<HZ>(m2.x, s2, r2, t2, h2, a);
            edge_acc<HZ>(m3.x, s3, r3, t3, h3, a);
        }
        for (; j < o1; ++j) {
            int2 m0 = meta[j];
            float s0 = score[j];
            uint4 r0 = ldrow(relb, (m0.x >> 17) & 0xFF, hc8);
            uint4 t0 = ldrow(tembb, m0.y & 511, hc8);
            uint4 h0 = zz;
            if (!HZ) h0 = ldrow(hidden_in, m0.x & 0x1FFFF, hc8);
            edge_acc<HZ>(m0.x, s0, r0, t0, h0, a);
        }
    }

    // --- transform via split-bf16 MFMA, one class slab at a time ---
    unsigned* lds_u = (unsigned*)lds_t;
    int rl = lane & 15;
    int t  = lane >> 4;
    int rt = w & 1;    // row-tile (nodes rt*16..rt*16+15)
    int ct = w >> 1;   // col-pair (nt = 2ct, 2ct+1)
    f32x4 accd[2];
    accd[0] = (f32x4){0.f, 0.f, 0.f, 0.f};
    accd[1] = (f32x4){0.f, 0.f, 0.f, 0.f};

    #pragma unroll
    for (int c = 0; c < 3; ++c) {
        __syncthreads();   // protect previous slab's reads
        {
            float4 v0 = a[2 * c];
            float4 v1 = a[2 * c + 1];
            unsigned p0 = packbf2(v0.x, v0.y);
            unsigned p1 = packbf2(v0.z, v0.w);
            unsigned p2 = packbf2(v1.x, v1.y);
            unsigned p3 = packbf2(v1.z, v1.w);
            unsigned q0 = packbf2(v0.x - bflo(p0), v0.y - bfhi(p0));
            unsigned q1 = packbf2(v0.z - bflo(p1), v0.w - bfhi(p1));
            unsigned q2 = packbf2(v1.x - bflo(p2), v1.y - bfhi(p2));
            unsigned q3 = packbf2(v1.z - bflo(p3), v1.w - bfhi(p3));
            *(uint4*)(lds_u + gid * SPITCH + hc * 4)      = make_uint4(p0, p1, p2, p3);
            *(uint4*)(lds_u + gid * SPITCH + 32 + hc * 4) = make_uint4(q0, q1, q2, q3);
        }
        __syncthreads();
        #pragma unroll
        for (int ks = 0; ks < 2; ++ks) {
            const unsigned* rowp = lds_u + (rt * 16 + rl) * SPITCH + ks * 16 + t * 4;
            vbf8 ah = *(const vbf8*)rowp;
            vbf8 al = *(const vbf8*)(rowp + 32);
            #pragma unroll
            for (int b = 0; b < 2; ++b) {
                int nt = ct * 2 + b;
                const ushort* bp = WTB +
                    (size_t)((((c * 2) * 2 + ks) * 4 + nt) * 64 + lane) * 8;
                vbf8 bh = *(const vbf8*)bp;
                vbf8 bl = *(const vbf8*)(bp + 4096);   // hl=1 plane
                accd[b] = __builtin_amdgcn_mfma_f32_16x16x32_bf16(ah, bh, accd[b], 0, 0, 0);
                accd[b] = __builtin_amdgcn_mfma_f32_16x16x32_bf16(al, bh, accd[b], 0, 0, 0);
                accd[b] = __builtin_amdgcn_mfma_f32_16x16x32_bf16(ah, bl, accd[b], 0, 0, 0);
            }
        }
    }

    // D frag (col=lane&15, row=(lane>>4)*4+i) -> LDS [node][h] fp32
    __syncthreads();
    #pragma unroll
    for (int b = 0; b < 2; ++b)
        #pragma unroll
        for (int i = 0; i < 4; ++i)
            lds_t[(rt * 16 + t * 4 + i) * SPITCH + (ct * 2 + b) * 16 + rl] = accd[b][i];
    __syncthreads();

    // readback: thread owns node nd = gid, h-octet ho = hc
    float acc8[8];
    {
        const float4* rp = (const float4*)(lds_t + gid * SPITCH + hc8);
        float4 x = rp[0], y = rp[1];
        acc8[0] = x.x; acc8[1] = x.y; acc8[2] = x.z; acc8[3] = x.w;
        acc8[4] = y.x; acc8[5] = y.y; acc8[6] = y.z; acc8[7] = y.w;
    }

    {
        ushort* outp = hidden_out + (size_t)node * 64 + hc8;
        unsigned u0 = packbf2(fmaxf(acc8[0], 0.f), fmaxf(acc8[1], 0.f));
        unsigned u1 = packbf2(fmaxf(acc8[2], 0.f), fmaxf(acc8[3], 0.f));
        unsigned u2 = packbf2(fmaxf(acc8[4], 0.f), fmaxf(acc8[5], 0.f));
        unsigned u3 = packbf2(fmaxf(acc8[6], 0.f), fmaxf(acc8[7], 0.f));
        *(uint4*)outp = make_uint4(u0, u1, u2, u3);
    }

    // --- epilogue: proj for NEXT layer from fp32 acc (exact) ---
    if (PROJ) {
        float pa[AD];
        #pragma unroll
        for (int aa = 0; aa < AD; ++aa) pa[aa] = 0.f;
        #pragma unroll
        for (int i = 0; i < 8; ++i) {
            float hv = fmaxf(acc8[i], 0.f);
            #pragma unroll
            for (int aa = 0; aa < AD; ++aa)
                pa[aa] = fmaf(hv, W1next[aa * 192 + hc8 + i], pa[aa]);
        }
        __syncthreads();
        float* lds2 = lds_t;   // reuse as [256][AD]
        #pragma unroll
        for (int aa = 0; aa < AD; ++aa)
            lds2[tid * AD + aa] = pa[aa];
        __syncthreads();
        int nd = tid >> 3, aa = tid & 7;
        float v = 0.f;
        if (aa < AD) {
            #pragma unroll
            for (int ho = 0; ho < 8; ++ho)
                v += lds2[(nd * 8 + ho) * AD + aa];
        }
        proj_out[(size_t)(node0 + nd) * 8 + aa] = v;
    }
}

// ---------------------------------------------------------------------------
__global__ __launch_bounds__(256) void out_kernel(
    const ushort* __restrict__ hidden,   // bf16 [NN][64]
    const float* __restrict__ Wc,
    const float* __restrict__ bc,
    float* __restrict__ out)
{
    int i = blockIdx.x * 256 + threadIdx.x;
    if (i >= NOUT) return;
    float r = 0.f;
    if (i < NN) {
        const uint4* h4 = (const uint4*)(hidden + (size_t)i * 64);
        float acc = 0.f;
        #pragma unroll
        for (int q = 0; q < 8; ++q) {
            uint4 hv = h4[q];
            const float* wq = Wc + q * 8;
            acc = fmaf(bflo(hv.x), wq[0], acc);
            acc = fmaf(bfhi(hv.x), wq[1], acc);
            acc = fmaf(bflo(hv.y), wq[2], acc);
            acc = fmaf(bfhi(hv.y), wq[3], acc);
            acc = fmaf(bflo(hv.z), wq[4], acc);
            acc = fmaf(bfhi(hv.z), wq[5], acc);
            acc = fmaf(bflo(hv.w), wq[6], acc);
            acc = fmaf(bfhi(hv.w), wq[7], acc);
        }
        r = acc + bc[0];
    }
    out[i] = r;
}

// ---------------------------------------------------------------------------
extern "C" void kernel_launch(void* const* d_in, const int* in_sizes, int n_in,
                              void* d_out, int out_size, void* d_ws, size_t ws_size,
                              hipStream_t stream)
{
    const int*   batch_idx  = (const int*)d_in[0];
    const int*   src_idx    = (const int*)d_in[1];
    const int*   dst_idx    = (const int*)d_in[2];
    const int*   rel_idx    = (const int*)d_in[3];
    const int*   rel_time   = (const int*)d_in[4];
    const int*   query_rel  = (const int*)d_in[5];
    const float* rela_embed = (const float*)d_in[8];   // [3][231][64]
    const float* time_embed = (const float*)d_in[9];   // [365][64]
    const float* Wp         = (const float*)d_in[10];
    const float* Wn         = (const float*)d_in[11];
    const float* Wf         = (const float*)d_in[12];
    const float* W1         = (const float*)d_in[13];  // [3][5][192]
    const float* W2         = (const float*)d_in[14];  // [3][1][5]
    const float* Wc         = (const float*)d_in[15];  // [64]
    const float* bc         = (const float*)d_in[16];  // [1]
    float* out = (float*)d_out;

    char* ws = (char*)d_ws;
    ushort* hid0  = (ushort*)(ws + 0);           // 12.8 MB bf16
    ushort* hid1  = (ushort*)(ws + 12800000);    // 12.8 MB bf16
    float* projA  = (float*)(ws + 25600000);     //  3.2 MB
    float* projB  = (float*)(ws + 28800000);     //  3.2 MB
    float* score  = (float*)(ws + 32000000);     //  4.0 MB
    ushort* WTB   = (ushort*)(ws + 36000000);    //  48 KB bf16 split W frags
    float* Trel   = (float*)(ws + 36100000);     //  ~22 KB
    float* Tq     = (float*)(ws + 36130000);     //  ~22 KB
    int*   off    = (int*)  (ws + 36160000);     // 400 KB (NN+1)
    int2*  meta   = (int2*) (ws + 37400000);     //  8.0 MB
    int*   deg    = (int*)  (ws + 45400000);     // 400 KB -> ends 45.8 MB
    ushort* relb  = (ushort*)(ws + 45800000);    //  88.7 KB bf16 rela [3][231][64]
    ushort* tembb = (ushort*)(ws + 45950000);    //  46.7 KB bf16 temb [365][64]
    int*   tmp    = (int*)  (ws + 46600000);     // 400 KB
    ushort* rank  = (ushort*)(ws + 47000000);    //  2.0 MB (NE ushorts)
    int*   bsum   = (int*)  (ws + 49000000);     //  ~2 KB
    int*   bpref  = (int*)  (ws + 49010000);     //  ~2 KB

    prep_wtb_kernel<<<12, 256, 0, stream>>>(Wp, Wn, Wf, WTB);
    prep_tb_kernel<<<133, 256, 0, stream>>>(rela_embed, time_embed, relb, tembb);
    prep_tables_kernel<<<NL, 256, 0, stream>>>(rela_embed, W1, Trel, Tq);

    // --- counting sort by dst (rank captured in hist; scatter atomic-free) ---
    hipMemsetAsync(deg, 0, NN * sizeof(int), stream);
    hist_kernel<<<(NE + 255) / 256, 256, 0, stream>>>(dst_idx, deg, rank);
    scan1_kernel<<<NBLK1, 256, 0, stream>>>(deg, tmp, bsum);
    scan2_kernel<<<1, 512, 0, stream>>>(bsum, bpref);
    scan3_kernel<<<NBLK1, 256, 0, stream>>>(deg, tmp, bpref, off);
    sort_scatter_kernel<<<(NE + 255) / 256, 256, 0, stream>>>(
        dst_idx, src_idx, rel_idx, rel_time, batch_idx, query_rel,
        off, rank, Trel, Tq, W2, meta, score);

    // --- layers: L0 -> hid0/projA ; L1 hid0,projA -> hid1/projB ;
    //             L2 hid1,projB -> hid0 ---
    int grid = NBLK2;
    int sgrid = (NE + 255) / 256;
    {
        reduce_transform_kernel<true, true><<<grid, 256, 0, stream>>>(
            hid1, relb, tembb, score, meta, off,
            WTB, W1 + (size_t)1 * AD * 192, hid0, projA);
    }
    {
        score_kernel<<<sgrid, 256, 0, stream>>>(
            projA, Trel + (size_t)1 * NRL * 8, Tq + (size_t)1 * NRL * 8,
            W2 + 1 * AD, meta, score);
        reduce_transform_kernel<false, true><<<grid, 256, 0, stream>>>(
            hid0, relb + (size_t)1 * NRL * HD, tembb, score, meta, off,
            WTB, W1 + (size_t)2 * AD * 192, hid1, projB);
    }
    {
        score_kernel<<<sgrid, 256, 0, stream>>>(
            projB, Trel + (size_t)2 * NRL * 8, Tq + (size_t)2 * NRL * 8,
            W2 + 2 * AD, meta, score);
        reduce_transform_kernel<false, false><<<grid, 256, 0, stream>>>(
            hid1, relb + (size_t)2 * NRL * HD, tembb, score, meta, off,
            WTB, nullptr, hid0, nullptr);
    }

    out_kernel<<<(NOUT + 255) / 256, 256, 0, stream>>>(hid0, Wc, bc, out);
}